// Round 2
// 609.536 us; speedup vs baseline: 1.4510x; 1.4510x over previous
//
#include <hip/hip_runtime.h>
#include <hip/hip_bf16.h>

typedef __hip_bfloat16 bf16;
typedef __attribute__((ext_vector_type(8))) short short8;
typedef __attribute__((ext_vector_type(4))) float f32x4;

#define Bq   2
#define Tq   2048
#define Dq   2048
#define NHq  16
#define HDq  48
#define LATq 256
#define NLHq 8
#define QN   (NHq * HDq)    // 768
#define KVN  (NLHq * HDq)   // 384

__device__ __forceinline__ unsigned short f2u(float x) {
    __hip_bfloat16 h = __float2bfloat16(x);
    return *reinterpret_cast<unsigned short*>(&h);
}
__device__ __forceinline__ float u2f(unsigned short u) {
    return __uint_as_float((unsigned)u << 16);
}
__device__ __forceinline__ unsigned pk2(float a, float b) {
    return (unsigned)f2u(a) | ((unsigned)f2u(b) << 16);
}

// ==== MFMA GEMM: q = x @ Wq, [4096,2048]fp32 x [2048,768]fp32 -> bf16 ==========
// block 256 thr = 4 waves (2x2), tile 64x64, BK=32. A_lds[m][k] s40; B_lds[n][k]
// s40 with 16B-chunk XOR swizzle (chunk ^= (n>>2)&3) for conflict-light staging.
extern "C" __global__ void __launch_bounds__(256)
mla_qproj(const float* __restrict__ A, const float* __restrict__ B, bf16* __restrict__ C) {
    __shared__ short As[64 * 40];
    __shared__ short Bs[64 * 40];
    const int t  = threadIdx.x;
    const int m0 = blockIdx.x * 64;
    const int n0 = blockIdx.y * 64;
    const int w  = t >> 6;
    const int wm = (w & 1) * 32;
    const int wn = (w >> 1) * 32;
    const int l  = t & 63;
    const int lr = l & 15;
    const int quad = l >> 4;

    f32x4 acc[2][2];
    #pragma unroll
    for (int mi = 0; mi < 2; ++mi)
        #pragma unroll
        for (int ni = 0; ni < 2; ++ni) acc[mi][ni] = (f32x4){0.f, 0.f, 0.f, 0.f};

    int aoff[2], boff[2];
    #pragma unroll
    for (int mi = 0; mi < 2; ++mi) aoff[mi] = (wm + mi * 16 + lr) * 40 + quad * 8;
    #pragma unroll
    for (int ni = 0; ni < 2; ++ni) {
        const int n = wn + ni * 16 + lr;
        boff[ni] = n * 40 + (quad ^ ((n >> 2) & 3)) * 8;
    }

    for (int kt = 0; kt < Dq / 32; ++kt) {
        #pragma unroll
        for (int it = 0; it < 2; ++it) {              // A-tile 64x32: 512 float4
            const int idx = t + 256 * it;
            const int m = idx >> 3, k4 = idx & 7;
            const float4 a4 = *(const float4*)&A[(size_t)(m0 + m) * Dq + kt * 32 + k4 * 4];
            const unsigned u0 = f2u(a4.x) | ((unsigned)f2u(a4.y) << 16);
            const unsigned u1 = f2u(a4.z) | ((unsigned)f2u(a4.w) << 16);
            *(uint2*)&As[m * 40 + k4 * 4] = make_uint2(u0, u1);
        }
        #pragma unroll
        for (int it = 0; it < 2; ++it) {              // B-tile 32x64 transposed
            const int idx = t + 256 * it;
            const int k = idx >> 4, n4 = idx & 15;
            const float4 b4 = *(const float4*)&B[(size_t)(kt * 32 + k) * QN + n0 + n4 * 4];
            const float bb[4] = {b4.x, b4.y, b4.z, b4.w};
            #pragma unroll
            for (int j = 0; j < 4; ++j) {
                const int n = n4 * 4 + j;
                const int ch = (k >> 3) ^ ((n >> 2) & 3);
                Bs[n * 40 + ch * 8 + (k & 7)] = (short)f2u(bb[j]);
            }
        }
        __syncthreads();
        short8 af[2], bfr[2];
        #pragma unroll
        for (int mi = 0; mi < 2; ++mi) af[mi] = *(const short8*)&As[aoff[mi]];
        #pragma unroll
        for (int ni = 0; ni < 2; ++ni) bfr[ni] = *(const short8*)&Bs[boff[ni]];
        #pragma unroll
        for (int mi = 0; mi < 2; ++mi)
            #pragma unroll
            for (int ni = 0; ni < 2; ++ni)
                acc[mi][ni] = __builtin_amdgcn_mfma_f32_16x16x32_bf16(af[mi], bfr[ni], acc[mi][ni], 0, 0, 0);
        __syncthreads();
    }
    #pragma unroll
    for (int mi = 0; mi < 2; ++mi)
        #pragma unroll
        for (int ni = 0; ni < 2; ++ni) {
            const int col = n0 + wn + ni * 16 + lr;
            #pragma unroll
            for (int r = 0; r < 4; ++r) {
                const int row = m0 + wm + mi * 16 + quad * 4 + r;
                C[(size_t)row * QN + col] = __float2bfloat16(acc[mi][ni][r]);
            }
        }
}

// ==== MFMA GEMM: out = ao @ Wo, [4096,768]bf16 x [768,2048]fp32 -> fp32 ========
extern "C" __global__ void __launch_bounds__(256)
mla_oproj(const bf16* __restrict__ A, const float* __restrict__ B, float* __restrict__ C) {
    __shared__ short As[64 * 40];
    __shared__ short Bs[64 * 40];
    const int t  = threadIdx.x;
    const int m0 = blockIdx.x * 64;
    const int n0 = blockIdx.y * 64;
    const int w  = t >> 6;
    const int wm = (w & 1) * 32;
    const int wn = (w >> 1) * 32;
    const int l  = t & 63;
    const int lr = l & 15;
    const int quad = l >> 4;

    f32x4 acc[2][2];
    #pragma unroll
    for (int mi = 0; mi < 2; ++mi)
        #pragma unroll
        for (int ni = 0; ni < 2; ++ni) acc[mi][ni] = (f32x4){0.f, 0.f, 0.f, 0.f};

    int aoff[2], boff[2];
    #pragma unroll
    for (int mi = 0; mi < 2; ++mi) aoff[mi] = (wm + mi * 16 + lr) * 40 + quad * 8;
    #pragma unroll
    for (int ni = 0; ni < 2; ++ni) {
        const int n = wn + ni * 16 + lr;
        boff[ni] = n * 40 + (quad ^ ((n >> 2) & 3)) * 8;
    }

    for (int kt = 0; kt < QN / 32; ++kt) {
        {                                             // A-tile 64x32 bf16: 256 uint4
            const int m = t >> 2, k8 = t & 3;
            *(uint4*)&As[m * 40 + k8 * 8] =
                *(const uint4*)&A[(size_t)(m0 + m) * QN + kt * 32 + k8 * 8];
        }
        #pragma unroll
        for (int it = 0; it < 2; ++it) {              // B-tile 32x64 transposed
            const int idx = t + 256 * it;
            const int k = idx >> 4, n4 = idx & 15;
            const float4 b4 = *(const float4*)&B[(size_t)(kt * 32 + k) * Dq + n0 + n4 * 4];
            const float bb[4] = {b4.x, b4.y, b4.z, b4.w};
            #pragma unroll
            for (int j = 0; j < 4; ++j) {
                const int n = n4 * 4 + j;
                const int ch = (k >> 3) ^ ((n >> 2) & 3);
                Bs[n * 40 + ch * 8 + (k & 7)] = (short)f2u(bb[j]);
            }
        }
        __syncthreads();
        short8 af[2], bfr[2];
        #pragma unroll
        for (int mi = 0; mi < 2; ++mi) af[mi] = *(const short8*)&As[aoff[mi]];
        #pragma unroll
        for (int ni = 0; ni < 2; ++ni) bfr[ni] = *(const short8*)&Bs[boff[ni]];
        #pragma unroll
        for (int mi = 0; mi < 2; ++mi)
            #pragma unroll
            for (int ni = 0; ni < 2; ++ni)
                acc[mi][ni] = __builtin_amdgcn_mfma_f32_16x16x32_bf16(af[mi], bfr[ni], acc[mi][ni], 0, 0, 0);
        __syncthreads();
    }
    #pragma unroll
    for (int mi = 0; mi < 2; ++mi)
        #pragma unroll
        for (int ni = 0; ni < 2; ++ni) {
            const int col = n0 + wn + ni * 16 + lr;
            #pragma unroll
            for (int r = 0; r < 4; ++r) {
                const int row = m0 + wm + mi * 16 + quad * 4 + r;
                C[(size_t)row * Dq + col] = acc[mi][ni][r];
            }
        }
}

// ---- lat = rmsnorm(x @ Wkv) : [4096,2048]x[2048,256] -> fp32, 8 rows/block ----
extern "C" __global__ void __launch_bounds__(256)
mla_kvlat(const float* __restrict__ x, const float* __restrict__ Wkv,
          const float* __restrict__ wn, float* __restrict__ lat) {
    __shared__ float xs[8][1024];
    __shared__ float red[8][256];
    const int r0 = blockIdx.x * 8;
    const int t = threadIdx.x;
    float acc[8];
    #pragma unroll
    for (int r = 0; r < 8; ++r) acc[r] = 0.f;

    for (int kc = 0; kc < 2; ++kc) {
        __syncthreads();
        #pragma unroll
        for (int n = 0; n < 8; ++n) {
            const int idx4 = t + 256 * n;
            const int r = idx4 >> 8, c4 = idx4 & 255;
            *(float4*)&xs[r][c4 * 4] =
                *(const float4*)&x[(size_t)(r0 + r) * Dq + kc * 1024 + c4 * 4];
        }
        __syncthreads();
        for (int k = 0; k < 1024; ++k) {
            const float w = Wkv[(size_t)(kc * 1024 + k) * LATq + t];
            #pragma unroll
            for (int r = 0; r < 8; ++r) acc[r] = fmaf(xs[r][k], w, acc[r]);
        }
    }
    #pragma unroll
    for (int r = 0; r < 8; ++r) red[r][t] = acc[r] * acc[r];
    __syncthreads();
    for (int s = 128; s > 0; s >>= 1) {
        if (t < s) {
            #pragma unroll
            for (int r = 0; r < 8; ++r) red[r][t] += red[r][t + s];
        }
        __syncthreads();
    }
    const float w = wn[t];
    #pragma unroll
    for (int r = 0; r < 8; ++r) {
        const float rr = rsqrtf(red[r][0] * (1.0f / LATq) + 1e-5f);
        lat[(size_t)(r0 + r) * LATq + t] = acc[r] * rr * w;
    }
}

// ---- k,v = lat @ Wk / lat @ Wv : [4096,256]x[256,384] -> bf16, 8 rows/block ---
extern "C" __global__ void __launch_bounds__(384)
mla_kvproj(const float* __restrict__ lat, const float* __restrict__ Wk,
           const float* __restrict__ Wv, bf16* __restrict__ ko, bf16* __restrict__ vo) {
    __shared__ float ls[8][LATq];
    const int r0 = blockIdx.x * 8;
    const int t = threadIdx.x;
    for (int idx = t; idx < 8 * LATq; idx += 384) {
        const int r = idx >> 8, c = idx & 255;
        ls[r][c] = lat[(size_t)(r0 + r) * LATq + c];
    }
    __syncthreads();
    float ak[8], av[8];
    #pragma unroll
    for (int r = 0; r < 8; ++r) { ak[r] = 0.f; av[r] = 0.f; }
    for (int k = 0; k < LATq; ++k) {
        const float wk = Wk[(size_t)k * KVN + t];
        const float wv = Wv[(size_t)k * KVN + t];
        #pragma unroll
        for (int r = 0; r < 8; ++r) {
            const float lv = ls[r][k];
            ak[r] = fmaf(lv, wk, ak[r]);
            av[r] = fmaf(lv, wv, av[r]);
        }
    }
    #pragma unroll
    for (int r = 0; r < 8; ++r) {
        ko[(size_t)(r0 + r) * KVN + t] = __float2bfloat16(ak[r]);
        vo[(size_t)(r0 + r) * KVN + t] = __float2bfloat16(av[r]);
    }
}

// ==== MFMA flash attention ====================================================
// S^T = K·Q^T and O^T = V^T·P^T via mfma_f32_16x16x32_bf16 (same fragment
// convention as the GEMMs above: A row=l&15 k=(l>>4)*8+j; B read as [n][k];
// C col=l&15 row=(l>>4)*4+r). Swapped operands keep softmax state (m, l,
// O-rescale) lane-local: output col = q = lane&15 in both products.
// Block = 128 thr (2 waves) = 64 q rows of one head; wave = 32 q rows as 2
// subtiles of 16 (K/V frags reused across subtiles). Per 64-key tile:
// Ks[64][72] row-major (d 48..63 zero-padded so QK runs K=64 in 2 steps),
// Vt[48][72] = V transposed at staging (pair-packed u32 writes). Stride 72:
// 16B-aligned ds_read_b128, 2-way banks (free). P (C-layout) round-trips
// through per-wave LDS scratch to reach B-frag layout; p rounded to bf16
// BEFORE the row-sum so numerator/denominator use identical weights.
// grid (16 heads, 32 qy, 2 b); qt = qy<16 ? 2qy : 63-2qy pairs heavy+light
// q-tiles on the same CU (linear block->CU assignment) for balance.
extern "C" __global__ void __launch_bounds__(128)
mla_attn(const bf16* __restrict__ q, const bf16* __restrict__ kk,
         const bf16* __restrict__ vv, bf16* __restrict__ ao) {
    __shared__ short Ks[64 * 72];
    __shared__ short Vt[48 * 72];
    __shared__ short Ps[2 * 2 * 16 * 72];
    const int t    = threadIdx.x;
    const int h    = blockIdx.x;
    const int g    = h >> 1;
    const int qy   = blockIdx.y;
    const int qt   = (qy < 16) ? (qy << 1) : (63 - (qy << 1));
    const int b    = blockIdx.z;
    const int w    = t >> 6;
    const int lr   = t & 15;
    const int quad = (t >> 4) & 3;
    const int Q0   = qt * 64;
    const float scale = 0.14433756729740643f;   // 1/sqrt(48)

    for (int i = t; i < 512; i += 128)          // zero-pad Ks cols 48..63 once
        *(unsigned*)&Ks[(i >> 3) * 72 + 48 + (i & 7) * 2] = 0u;

    // Q fragments (B-operand): lane holds Q[q = lr][d = ks*32 + quad*8 + j]
    short8 qf[2][2];
    int qg[2];
    #pragma unroll
    for (int st = 0; st < 2; ++st) {
        qg[st] = Q0 + w * 32 + st * 16 + lr;
        const bf16* qr = q + (size_t)(b * Tq + qg[st]) * QN + h * HDq;
        qf[st][0] = *(const short8*)(qr + quad * 8);
        short8 z = {0, 0, 0, 0, 0, 0, 0, 0};
        qf[st][1] = (quad < 2) ? *(const short8*)(qr + 32 + quad * 8) : z;
    }

    const bf16* kb = kk + (size_t)b * Tq * KVN + g * HDq;
    const bf16* vb = vv + (size_t)b * Tq * KVN + g * HDq;

    float m[2] = {-1e30f, -1e30f}, l[2] = {0.f, 0.f};
    f32x4 acc[2][3];
    #pragma unroll
    for (int st = 0; st < 2; ++st)
        #pragma unroll
        for (int dm = 0; dm < 3; ++dm) acc[st][dm] = (f32x4){0.f, 0.f, 0.f, 0.f};

    short* Pw = &Ps[w * 2 * 16 * 72];

    for (int tl = 0; tl <= qt; ++tl) {
        __syncthreads();
        for (int task = t; task < 576; task += 128) {
            if (task < 384) {                   // K: 64 rows x 6 chunks of 8 bf16
                const int row = task / 6, dg = task - row * 6;
                *(uint4*)&Ks[row * 72 + dg * 8] =
                    *(const uint4*)(kb + (size_t)(tl * 64 + row) * KVN + dg * 8);
            } else {                            // V^T: 32 key-pairs x 6 d-chunks
                const int vtk = task - 384;
                const int kp = vtk & 31, dg = vtk >> 5;
                uint4 a4 = *(const uint4*)(vb + (size_t)(tl * 64 + 2 * kp) * KVN + dg * 8);
                uint4 b4 = *(const uint4*)(vb + (size_t)(tl * 64 + 2 * kp + 1) * KVN + dg * 8);
                const unsigned short* ua = (const unsigned short*)&a4;
                const unsigned short* ub = (const unsigned short*)&b4;
                #pragma unroll
                for (int j = 0; j < 8; ++j)
                    *(unsigned*)&Vt[(dg * 8 + j) * 72 + 2 * kp] =
                        (unsigned)ua[j] | ((unsigned)ub[j] << 16);
            }
        }
        __syncthreads();

        // S^T[key][q] = K·Q^T : lane holds key = mt*16 + quad*4 + r, q = lr
        f32x4 sc[2][4];
        #pragma unroll
        for (int mt = 0; mt < 4; ++mt) {
            const short8 k0 = *(const short8*)&Ks[(mt * 16 + lr) * 72 + quad * 8];
            const short8 k1 = *(const short8*)&Ks[(mt * 16 + lr) * 72 + 32 + quad * 8];
            #pragma unroll
            for (int st = 0; st < 2; ++st) {
                f32x4 s = (f32x4){0.f, 0.f, 0.f, 0.f};
                s = __builtin_amdgcn_mfma_f32_16x16x32_bf16(k0, qf[st][0], s, 0, 0, 0);
                s = __builtin_amdgcn_mfma_f32_16x16x32_bf16(k1, qf[st][1], s, 0, 0, 0);
                sc[st][mt] = s;
            }
        }
        if (tl == qt) {                         // diagonal tile: mask key > q
            #pragma unroll
            for (int st = 0; st < 2; ++st) {
                const int qloc = w * 32 + st * 16 + lr;
                #pragma unroll
                for (int mt = 0; mt < 4; ++mt)
                    #pragma unroll
                    for (int r = 0; r < 4; ++r)
                        if (mt * 16 + quad * 4 + r > qloc) sc[st][mt][r] = -1e30f;
            }
        }
        #pragma unroll
        for (int st = 0; st < 2; ++st) {
            float mx = -1e30f;
            #pragma unroll
            for (int mt = 0; mt < 4; ++mt)
                #pragma unroll
                for (int r = 0; r < 4; ++r) mx = fmaxf(mx, sc[st][mt][r]);
            mx = fmaxf(mx, __shfl_xor(mx, 16));
            mx = fmaxf(mx, __shfl_xor(mx, 32));
            const float mn = fmaxf(m[st], mx * scale);
            const float f  = __expf(m[st] - mn);
            m[st] = mn;
            float rs = 0.f;
            #pragma unroll
            for (int mt = 0; mt < 4; ++mt)
                #pragma unroll
                for (int r = 0; r < 4; ++r) {
                    const float p = u2f(f2u(__expf(fmaf(sc[st][mt][r], scale, -mn))));
                    sc[st][mt][r] = p;          // bf16-rounded weight
                    rs += p;
                }
            rs += __shfl_xor(rs, 16);
            rs += __shfl_xor(rs, 32);
            l[st] = l[st] * f + rs;
            #pragma unroll
            for (int dm = 0; dm < 3; ++dm)
                #pragma unroll
                for (int r = 0; r < 4; ++r) acc[st][dm][r] *= f;
            // pack P to per-wave scratch: Pst[q=lr][key], key pairs -> u32
            short* Pst = Pw + st * 16 * 72;
            #pragma unroll
            for (int mt = 0; mt < 4; ++mt) {
                unsigned* pw = (unsigned*)&Pst[lr * 72 + mt * 16 + quad * 4];
                pw[0] = pk2(sc[st][mt][0], sc[st][mt][1]);
                pw[1] = pk2(sc[st][mt][2], sc[st][mt][3]);
            }
        }
        // B-frag read-back: lane holds P[q=lr][key = ks*32 + quad*8 + j]
        short8 pf[2][2];
        #pragma unroll
        for (int st = 0; st < 2; ++st) {
            const short* Pst = Pw + st * 16 * 72;
            pf[st][0] = *(const short8*)&Pst[lr * 72 + quad * 8];
            pf[st][1] = *(const short8*)&Pst[lr * 72 + 32 + quad * 8];
        }
        // O^T[d][q] += V^T·P^T : lane accumulates d = dm*16 + quad*4 + r, q = lr
        #pragma unroll
        for (int dm = 0; dm < 3; ++dm) {
            const short8 v0 = *(const short8*)&Vt[(dm * 16 + lr) * 72 + quad * 8];
            const short8 v1 = *(const short8*)&Vt[(dm * 16 + lr) * 72 + 32 + quad * 8];
            #pragma unroll
            for (int st = 0; st < 2; ++st) {
                acc[st][dm] = __builtin_amdgcn_mfma_f32_16x16x32_bf16(v0, pf[st][0], acc[st][dm], 0, 0, 0);
                acc[st][dm] = __builtin_amdgcn_mfma_f32_16x16x32_bf16(v1, pf[st][1], acc[st][dm], 0, 0, 0);
            }
        }
    }

    #pragma unroll
    for (int st = 0; st < 2; ++st) {
        const float inv = 1.0f / l[st];
        bf16* orow = ao + (size_t)(b * Tq + qg[st]) * QN + h * HDq;
        #pragma unroll
        for (int dm = 0; dm < 3; ++dm) {
            const unsigned w0 = pk2(acc[st][dm][0] * inv, acc[st][dm][1] * inv);
            const unsigned w1 = pk2(acc[st][dm][2] * inv, acc[st][dm][3] * inv);
            *(uint2*)(orow + dm * 16 + quad * 4) = make_uint2(w0, w1);
        }
    }
}

extern "C" void kernel_launch(void* const* d_in, const int* in_sizes, int n_in,
                              void* d_out, int out_size, void* d_ws, size_t ws_size,
                              hipStream_t stream) {
    const float* x   = (const float*)d_in[0];
    // d_in[1]: causal mask — static tril, applied analytically in mla_attn
    const float* Wq  = (const float*)d_in[2];
    const float* Wkv = (const float*)d_in[3];
    const float* wn  = (const float*)d_in[4];
    const float* Wk  = (const float*)d_in[5];
    const float* Wv  = (const float*)d_in[6];
    const float* Wo  = (const float*)d_in[7];
    float* out = (float*)d_out;

    const int M = Bq * Tq;                          // 4096
    // d_out staging (dead before oproj rewrites it): [0 : 6.29M) q bf16
    bf16*  qws = (bf16*)d_out;
    // ws: k bf16 3.15M | v bf16 3.15M | ao bf16 6.29M (lat fp32 overlays ao)
    bf16*  kws = (bf16*)d_ws;
    bf16*  vws = kws + (size_t)M * KVN;
    bf16*  aob = vws + (size_t)M * KVN;
    float* lat = (float*)aob;

    mla_qproj <<<dim3(M / 64, QN / 64), 256, 0, stream>>>(x, Wq, qws);
    mla_kvlat <<<M / 8, 256, 0, stream>>>(x, Wkv, wn, lat);
    mla_kvproj<<<M / 8, 384, 0, stream>>>(lat, Wk, Wv, kws, vws);
    mla_attn  <<<dim3(NHq, 32, Bq), 128, 0, stream>>>(qws, kws, vws, aob);
    mla_oproj <<<dim3(M / 64, Dq / 64), 256, 0, stream>>>(aob, Wo, out);
}

// Round 3
// 405.260 us; speedup vs baseline: 2.1823x; 1.5041x over previous
//
#include <hip/hip_runtime.h>
#include <hip/hip_bf16.h>

typedef __hip_bfloat16 bf16;
typedef __attribute__((ext_vector_type(8))) short short8;
typedef __attribute__((ext_vector_type(4))) float f32x4;

#define Bq   2
#define Tq   2048
#define Dq   2048
#define NHq  16
#define HDq  48
#define LATq 256
#define NLHq 8
#define QN   (NHq * HDq)    // 768
#define KVN  (NLHq * HDq)   // 384

__device__ __forceinline__ unsigned short f2u(float x) {
    __hip_bfloat16 h = __float2bfloat16(x);
    return *reinterpret_cast<unsigned short*>(&h);
}
__device__ __forceinline__ float u2f(unsigned short u) {
    return __uint_as_float((unsigned)u << 16);
}
__device__ __forceinline__ unsigned pk2(float a, float b) {
    return (unsigned)f2u(a) | ((unsigned)f2u(b) << 16);
}

// ==== MFMA GEMM: q = x @ Wq, [4096,2048]fp32 x [2048,768]fp32 -> bf16 ==========
// block 256 thr = 4 waves (2x2), tile 64x64, BK=32. A_lds[m][k] s40; B_lds[n][k]
// s40 with 16B-chunk XOR swizzle (chunk ^= (n>>2)&3) for conflict-light staging.
extern "C" __global__ void __launch_bounds__(256)
mla_qproj(const float* __restrict__ A, const float* __restrict__ B, bf16* __restrict__ C) {
    __shared__ short As[64 * 40];
    __shared__ short Bs[64 * 40];
    const int t  = threadIdx.x;
    const int m0 = blockIdx.x * 64;
    const int n0 = blockIdx.y * 64;
    const int w  = t >> 6;
    const int wm = (w & 1) * 32;
    const int wn = (w >> 1) * 32;
    const int l  = t & 63;
    const int lr = l & 15;
    const int quad = l >> 4;

    f32x4 acc[2][2];
    #pragma unroll
    for (int mi = 0; mi < 2; ++mi)
        #pragma unroll
        for (int ni = 0; ni < 2; ++ni) acc[mi][ni] = (f32x4){0.f, 0.f, 0.f, 0.f};

    int aoff[2], boff[2];
    #pragma unroll
    for (int mi = 0; mi < 2; ++mi) aoff[mi] = (wm + mi * 16 + lr) * 40 + quad * 8;
    #pragma unroll
    for (int ni = 0; ni < 2; ++ni) {
        const int n = wn + ni * 16 + lr;
        boff[ni] = n * 40 + (quad ^ ((n >> 2) & 3)) * 8;
    }

    for (int kt = 0; kt < Dq / 32; ++kt) {
        #pragma unroll
        for (int it = 0; it < 2; ++it) {              // A-tile 64x32: 512 float4
            const int idx = t + 256 * it;
            const int m = idx >> 3, k4 = idx & 7;
            const float4 a4 = *(const float4*)&A[(size_t)(m0 + m) * Dq + kt * 32 + k4 * 4];
            const unsigned u0 = f2u(a4.x) | ((unsigned)f2u(a4.y) << 16);
            const unsigned u1 = f2u(a4.z) | ((unsigned)f2u(a4.w) << 16);
            *(uint2*)&As[m * 40 + k4 * 4] = make_uint2(u0, u1);
        }
        #pragma unroll
        for (int it = 0; it < 2; ++it) {              // B-tile 32x64 transposed
            const int idx = t + 256 * it;
            const int k = idx >> 4, n4 = idx & 15;
            const float4 b4 = *(const float4*)&B[(size_t)(kt * 32 + k) * QN + n0 + n4 * 4];
            const float bb[4] = {b4.x, b4.y, b4.z, b4.w};
            #pragma unroll
            for (int j = 0; j < 4; ++j) {
                const int n = n4 * 4 + j;
                const int ch = (k >> 3) ^ ((n >> 2) & 3);
                Bs[n * 40 + ch * 8 + (k & 7)] = (short)f2u(bb[j]);
            }
        }
        __syncthreads();
        short8 af[2], bfr[2];
        #pragma unroll
        for (int mi = 0; mi < 2; ++mi) af[mi] = *(const short8*)&As[aoff[mi]];
        #pragma unroll
        for (int ni = 0; ni < 2; ++ni) bfr[ni] = *(const short8*)&Bs[boff[ni]];
        #pragma unroll
        for (int mi = 0; mi < 2; ++mi)
            #pragma unroll
            for (int ni = 0; ni < 2; ++ni)
                acc[mi][ni] = __builtin_amdgcn_mfma_f32_16x16x32_bf16(af[mi], bfr[ni], acc[mi][ni], 0, 0, 0);
        __syncthreads();
    }
    #pragma unroll
    for (int mi = 0; mi < 2; ++mi)
        #pragma unroll
        for (int ni = 0; ni < 2; ++ni) {
            const int col = n0 + wn + ni * 16 + lr;
            #pragma unroll
            for (int r = 0; r < 4; ++r) {
                const int row = m0 + wm + mi * 16 + quad * 4 + r;
                C[(size_t)row * QN + col] = __float2bfloat16(acc[mi][ni][r]);
            }
        }
}

// ==== MFMA GEMM: xkv = x @ Wkv, [4096,2048]fp32 x [2048,256]fp32 -> fp32 =======
// qproj structure, N=256 (grid 64x4), fp32 C-write (rmsnorm needs fp32 input).
extern "C" __global__ void __launch_bounds__(256)
mla_kvlat(const float* __restrict__ A, const float* __restrict__ B, float* __restrict__ C) {
    __shared__ short As[64 * 40];
    __shared__ short Bs[64 * 40];
    const int t  = threadIdx.x;
    const int m0 = blockIdx.x * 64;
    const int n0 = blockIdx.y * 64;
    const int w  = t >> 6;
    const int wm = (w & 1) * 32;
    const int wn = (w >> 1) * 32;
    const int l  = t & 63;
    const int lr = l & 15;
    const int quad = l >> 4;

    f32x4 acc[2][2];
    #pragma unroll
    for (int mi = 0; mi < 2; ++mi)
        #pragma unroll
        for (int ni = 0; ni < 2; ++ni) acc[mi][ni] = (f32x4){0.f, 0.f, 0.f, 0.f};

    int aoff[2], boff[2];
    #pragma unroll
    for (int mi = 0; mi < 2; ++mi) aoff[mi] = (wm + mi * 16 + lr) * 40 + quad * 8;
    #pragma unroll
    for (int ni = 0; ni < 2; ++ni) {
        const int n = wn + ni * 16 + lr;
        boff[ni] = n * 40 + (quad ^ ((n >> 2) & 3)) * 8;
    }

    for (int kt = 0; kt < Dq / 32; ++kt) {
        #pragma unroll
        for (int it = 0; it < 2; ++it) {              // A-tile 64x32: 512 float4
            const int idx = t + 256 * it;
            const int m = idx >> 3, k4 = idx & 7;
            const float4 a4 = *(const float4*)&A[(size_t)(m0 + m) * Dq + kt * 32 + k4 * 4];
            const unsigned u0 = f2u(a4.x) | ((unsigned)f2u(a4.y) << 16);
            const unsigned u1 = f2u(a4.z) | ((unsigned)f2u(a4.w) << 16);
            *(uint2*)&As[m * 40 + k4 * 4] = make_uint2(u0, u1);
        }
        #pragma unroll
        for (int it = 0; it < 2; ++it) {              // B-tile 32x64 transposed
            const int idx = t + 256 * it;
            const int k = idx >> 4, n4 = idx & 15;
            const float4 b4 = *(const float4*)&B[(size_t)(kt * 32 + k) * LATq + n0 + n4 * 4];
            const float bb[4] = {b4.x, b4.y, b4.z, b4.w};
            #pragma unroll
            for (int j = 0; j < 4; ++j) {
                const int n = n4 * 4 + j;
                const int ch = (k >> 3) ^ ((n >> 2) & 3);
                Bs[n * 40 + ch * 8 + (k & 7)] = (short)f2u(bb[j]);
            }
        }
        __syncthreads();
        short8 af[2], bfr[2];
        #pragma unroll
        for (int mi = 0; mi < 2; ++mi) af[mi] = *(const short8*)&As[aoff[mi]];
        #pragma unroll
        for (int ni = 0; ni < 2; ++ni) bfr[ni] = *(const short8*)&Bs[boff[ni]];
        #pragma unroll
        for (int mi = 0; mi < 2; ++mi)
            #pragma unroll
            for (int ni = 0; ni < 2; ++ni)
                acc[mi][ni] = __builtin_amdgcn_mfma_f32_16x16x32_bf16(af[mi], bfr[ni], acc[mi][ni], 0, 0, 0);
        __syncthreads();
    }
    #pragma unroll
    for (int mi = 0; mi < 2; ++mi)
        #pragma unroll
        for (int ni = 0; ni < 2; ++ni) {
            const int col = n0 + wn + ni * 16 + lr;
            #pragma unroll
            for (int r = 0; r < 4; ++r) {
                const int row = m0 + wm + mi * 16 + quad * 4 + r;
                C[(size_t)row * LATq + col] = acc[mi][ni][r];
            }
        }
}

// ---- lat = rmsnorm(xkv)*wn : [4096,256]fp32 -> bf16. 1 wave per row. ----------
extern "C" __global__ void __launch_bounds__(256)
mla_kvrms(const float* __restrict__ xkv, const float* __restrict__ wn,
          bf16* __restrict__ lat) {
    const int t = threadIdx.x;
    const int row = blockIdx.x * 4 + (t >> 6);
    const int lane = t & 63;
    const float4 v = *(const float4*)&xkv[(size_t)row * LATq + lane * 4];
    float ss = v.x * v.x + v.y * v.y + v.z * v.z + v.w * v.w;
    ss += __shfl_xor(ss, 1);  ss += __shfl_xor(ss, 2);  ss += __shfl_xor(ss, 4);
    ss += __shfl_xor(ss, 8);  ss += __shfl_xor(ss, 16); ss += __shfl_xor(ss, 32);
    const float rr = rsqrtf(ss * (1.0f / LATq) + 1e-5f);
    const float4 g = *(const float4*)&wn[lane * 4];
    const unsigned w0 = pk2(v.x * rr * g.x, v.y * rr * g.y);
    const unsigned w1 = pk2(v.z * rr * g.z, v.w * rr * g.w);
    *(uint2*)&lat[(size_t)row * LATq + lane * 4] = make_uint2(w0, w1);
}

// ==== MFMA GEMM: k/v = lat @ Wk|Wv, [4096,256]bf16 x [256,384]fp32 -> bf16 =====
// oproj structure (A bf16 direct uint4 staging), K=256 -> 8 k-steps.
// grid (64, 6, 2): z=0 -> Wk->ko, z=1 -> Wv->vo.
extern "C" __global__ void __launch_bounds__(256)
mla_kvproj(const bf16* __restrict__ A, const float* __restrict__ Bk,
           const float* __restrict__ Bv, bf16* __restrict__ ko, bf16* __restrict__ vo) {
    __shared__ short As[64 * 40];
    __shared__ short Bs[64 * 40];
    const int t  = threadIdx.x;
    const int m0 = blockIdx.x * 64;
    const int n0 = blockIdx.y * 64;
    const float* B = blockIdx.z ? Bv : Bk;
    bf16* C = blockIdx.z ? vo : ko;
    const int w  = t >> 6;
    const int wm = (w & 1) * 32;
    const int wn = (w >> 1) * 32;
    const int l  = t & 63;
    const int lr = l & 15;
    const int quad = l >> 4;

    f32x4 acc[2][2];
    #pragma unroll
    for (int mi = 0; mi < 2; ++mi)
        #pragma unroll
        for (int ni = 0; ni < 2; ++ni) acc[mi][ni] = (f32x4){0.f, 0.f, 0.f, 0.f};

    int aoff[2], boff[2];
    #pragma unroll
    for (int mi = 0; mi < 2; ++mi) aoff[mi] = (wm + mi * 16 + lr) * 40 + quad * 8;
    #pragma unroll
    for (int ni = 0; ni < 2; ++ni) {
        const int n = wn + ni * 16 + lr;
        boff[ni] = n * 40 + (quad ^ ((n >> 2) & 3)) * 8;
    }

    for (int kt = 0; kt < LATq / 32; ++kt) {
        {                                             // A-tile 64x32 bf16: 256 uint4
            const int m = t >> 2, k8 = t & 3;
            *(uint4*)&As[m * 40 + k8 * 8] =
                *(const uint4*)&A[(size_t)(m0 + m) * LATq + kt * 32 + k8 * 8];
        }
        #pragma unroll
        for (int it = 0; it < 2; ++it) {              // B-tile 32x64 transposed
            const int idx = t + 256 * it;
            const int k = idx >> 4, n4 = idx & 15;
            const float4 b4 = *(const float4*)&B[(size_t)(kt * 32 + k) * KVN + n0 + n4 * 4];
            const float bb[4] = {b4.x, b4.y, b4.z, b4.w};
            #pragma unroll
            for (int j = 0; j < 4; ++j) {
                const int n = n4 * 4 + j;
                const int ch = (k >> 3) ^ ((n >> 2) & 3);
                Bs[n * 40 + ch * 8 + (k & 7)] = (short)f2u(bb[j]);
            }
        }
        __syncthreads();
        short8 af[2], bfr[2];
        #pragma unroll
        for (int mi = 0; mi < 2; ++mi) af[mi] = *(const short8*)&As[aoff[mi]];
        #pragma unroll
        for (int ni = 0; ni < 2; ++ni) bfr[ni] = *(const short8*)&Bs[boff[ni]];
        #pragma unroll
        for (int mi = 0; mi < 2; ++mi)
            #pragma unroll
            for (int ni = 0; ni < 2; ++ni)
                acc[mi][ni] = __builtin_amdgcn_mfma_f32_16x16x32_bf16(af[mi], bfr[ni], acc[mi][ni], 0, 0, 0);
        __syncthreads();
    }
    #pragma unroll
    for (int mi = 0; mi < 2; ++mi)
        #pragma unroll
        for (int ni = 0; ni < 2; ++ni) {
            const int col = n0 + wn + ni * 16 + lr;
            #pragma unroll
            for (int r = 0; r < 4; ++r) {
                const int row = m0 + wm + mi * 16 + quad * 4 + r;
                C[(size_t)row * KVN + col] = __float2bfloat16(acc[mi][ni][r]);
            }
        }
}

// ==== MFMA GEMM: out = ao @ Wo, [4096,768]bf16 x [768,2048]fp32 -> fp32 ========
extern "C" __global__ void __launch_bounds__(256)
mla_oproj(const bf16* __restrict__ A, const float* __restrict__ B, float* __restrict__ C) {
    __shared__ short As[64 * 40];
    __shared__ short Bs[64 * 40];
    const int t  = threadIdx.x;
    const int m0 = blockIdx.x * 64;
    const int n0 = blockIdx.y * 64;
    const int w  = t >> 6;
    const int wm = (w & 1) * 32;
    const int wn = (w >> 1) * 32;
    const int l  = t & 63;
    const int lr = l & 15;
    const int quad = l >> 4;

    f32x4 acc[2][2];
    #pragma unroll
    for (int mi = 0; mi < 2; ++mi)
        #pragma unroll
        for (int ni = 0; ni < 2; ++ni) acc[mi][ni] = (f32x4){0.f, 0.f, 0.f, 0.f};

    int aoff[2], boff[2];
    #pragma unroll
    for (int mi = 0; mi < 2; ++mi) aoff[mi] = (wm + mi * 16 + lr) * 40 + quad * 8;
    #pragma unroll
    for (int ni = 0; ni < 2; ++ni) {
        const int n = wn + ni * 16 + lr;
        boff[ni] = n * 40 + (quad ^ ((n >> 2) & 3)) * 8;
    }

    for (int kt = 0; kt < QN / 32; ++kt) {
        {                                             // A-tile 64x32 bf16: 256 uint4
            const int m = t >> 2, k8 = t & 3;
            *(uint4*)&As[m * 40 + k8 * 8] =
                *(const uint4*)&A[(size_t)(m0 + m) * QN + kt * 32 + k8 * 8];
        }
        #pragma unroll
        for (int it = 0; it < 2; ++it) {              // B-tile 32x64 transposed
            const int idx = t + 256 * it;
            const int k = idx >> 4, n4 = idx & 15;
            const float4 b4 = *(const float4*)&B[(size_t)(kt * 32 + k) * Dq + n0 + n4 * 4];
            const float bb[4] = {b4.x, b4.y, b4.z, b4.w};
            #pragma unroll
            for (int j = 0; j < 4; ++j) {
                const int n = n4 * 4 + j;
                const int ch = (k >> 3) ^ ((n >> 2) & 3);
                Bs[n * 40 + ch * 8 + (k & 7)] = (short)f2u(bb[j]);
            }
        }
        __syncthreads();
        short8 af[2], bfr[2];
        #pragma unroll
        for (int mi = 0; mi < 2; ++mi) af[mi] = *(const short8*)&As[aoff[mi]];
        #pragma unroll
        for (int ni = 0; ni < 2; ++ni) bfr[ni] = *(const short8*)&Bs[boff[ni]];
        #pragma unroll
        for (int mi = 0; mi < 2; ++mi)
            #pragma unroll
            for (int ni = 0; ni < 2; ++ni)
                acc[mi][ni] = __builtin_amdgcn_mfma_f32_16x16x32_bf16(af[mi], bfr[ni], acc[mi][ni], 0, 0, 0);
        __syncthreads();
    }
    #pragma unroll
    for (int mi = 0; mi < 2; ++mi)
        #pragma unroll
        for (int ni = 0; ni < 2; ++ni) {
            const int col = n0 + wn + ni * 16 + lr;
            #pragma unroll
            for (int r = 0; r < 4; ++r) {
                const int row = m0 + wm + mi * 16 + quad * 4 + r;
                C[(size_t)row * Dq + col] = acc[mi][ni][r];
            }
        }
}

// ==== MFMA flash attention ====================================================
// S^T = K·Q^T and O^T = V^T·P^T via mfma_f32_16x16x32_bf16 (same fragment
// convention as the GEMMs above: A row=l&15 k=(l>>4)*8+j; B read as [n][k];
// C col=l&15 row=(l>>4)*4+r). Swapped operands keep softmax state (m, l,
// O-rescale) lane-local: output col = q = lane&15 in both products.
// Block = 128 thr (2 waves) = 64 q rows of one head; wave = 32 q rows as 2
// subtiles of 16 (K/V frags reused across subtiles). Per 64-key tile:
// Ks[64][72] row-major (d 48..63 zero-padded so QK runs K=64 in 2 steps),
// Vt[48][72] = V transposed at staging (pair-packed u32 writes). Stride 72:
// 16B-aligned ds_read_b128, 2-way banks (free). P (C-layout) round-trips
// through per-wave LDS scratch to reach B-frag layout; p rounded to bf16
// BEFORE the row-sum so numerator/denominator use identical weights.
// grid (16 heads, 32 qy, 2 b); qt = qy<16 ? 2qy : 63-2qy pairs heavy+light
// q-tiles on the same CU (linear block->CU assignment) for balance.
extern "C" __global__ void __launch_bounds__(128)
mla_attn(const bf16* __restrict__ q, const bf16* __restrict__ kk,
         const bf16* __restrict__ vv, bf16* __restrict__ ao) {
    __shared__ short Ks[64 * 72];
    __shared__ short Vt[48 * 72];
    __shared__ short Ps[2 * 2 * 16 * 72];
    const int t    = threadIdx.x;
    const int h    = blockIdx.x;
    const int g    = h >> 1;
    const int qy   = blockIdx.y;
    const int qt   = (qy < 16) ? (qy << 1) : (63 - (qy << 1));
    const int b    = blockIdx.z;
    const int w    = t >> 6;
    const int lr   = t & 15;
    const int quad = (t >> 4) & 3;
    const int Q0   = qt * 64;
    const float scale = 0.14433756729740643f;   // 1/sqrt(48)

    for (int i = t; i < 512; i += 128)          // zero-pad Ks cols 48..63 once
        *(unsigned*)&Ks[(i >> 3) * 72 + 48 + (i & 7) * 2] = 0u;

    // Q fragments (B-operand): lane holds Q[q = lr][d = ks*32 + quad*8 + j]
    short8 qf[2][2];
    int qg[2];
    #pragma unroll
    for (int st = 0; st < 2; ++st) {
        qg[st] = Q0 + w * 32 + st * 16 + lr;
        const bf16* qr = q + (size_t)(b * Tq + qg[st]) * QN + h * HDq;
        qf[st][0] = *(const short8*)(qr + quad * 8);
        short8 z = {0, 0, 0, 0, 0, 0, 0, 0};
        qf[st][1] = (quad < 2) ? *(const short8*)(qr + 32 + quad * 8) : z;
    }

    const bf16* kb = kk + (size_t)b * Tq * KVN + g * HDq;
    const bf16* vb = vv + (size_t)b * Tq * KVN + g * HDq;

    float m[2] = {-1e30f, -1e30f}, l[2] = {0.f, 0.f};
    f32x4 acc[2][3];
    #pragma unroll
    for (int st = 0; st < 2; ++st)
        #pragma unroll
        for (int dm = 0; dm < 3; ++dm) acc[st][dm] = (f32x4){0.f, 0.f, 0.f, 0.f};

    short* Pw = &Ps[w * 2 * 16 * 72];

    for (int tl = 0; tl <= qt; ++tl) {
        __syncthreads();
        for (int task = t; task < 576; task += 128) {
            if (task < 384) {                   // K: 64 rows x 6 chunks of 8 bf16
                const int row = task / 6, dg = task - row * 6;
                *(uint4*)&Ks[row * 72 + dg * 8] =
                    *(const uint4*)(kb + (size_t)(tl * 64 + row) * KVN + dg * 8);
            } else {                            // V^T: 32 key-pairs x 6 d-chunks
                const int vtk = task - 384;
                const int kp = vtk & 31, dg = vtk >> 5;
                uint4 a4 = *(const uint4*)(vb + (size_t)(tl * 64 + 2 * kp) * KVN + dg * 8);
                uint4 b4 = *(const uint4*)(vb + (size_t)(tl * 64 + 2 * kp + 1) * KVN + dg * 8);
                const unsigned short* ua = (const unsigned short*)&a4;
                const unsigned short* ub = (const unsigned short*)&b4;
                #pragma unroll
                for (int j = 0; j < 8; ++j)
                    *(unsigned*)&Vt[(dg * 8 + j) * 72 + 2 * kp] =
                        (unsigned)ua[j] | ((unsigned)ub[j] << 16);
            }
        }
        __syncthreads();

        // S^T[key][q] = K·Q^T : lane holds key = mt*16 + quad*4 + r, q = lr
        f32x4 sc[2][4];
        #pragma unroll
        for (int mt = 0; mt < 4; ++mt) {
            const short8 k0 = *(const short8*)&Ks[(mt * 16 + lr) * 72 + quad * 8];
            const short8 k1 = *(const short8*)&Ks[(mt * 16 + lr) * 72 + 32 + quad * 8];
            #pragma unroll
            for (int st = 0; st < 2; ++st) {
                f32x4 s = (f32x4){0.f, 0.f, 0.f, 0.f};
                s = __builtin_amdgcn_mfma_f32_16x16x32_bf16(k0, qf[st][0], s, 0, 0, 0);
                s = __builtin_amdgcn_mfma_f32_16x16x32_bf16(k1, qf[st][1], s, 0, 0, 0);
                sc[st][mt] = s;
            }
        }
        if (tl == qt) {                         // diagonal tile: mask key > q
            #pragma unroll
            for (int st = 0; st < 2; ++st) {
                const int qloc = w * 32 + st * 16 + lr;
                #pragma unroll
                for (int mt = 0; mt < 4; ++mt)
                    #pragma unroll
                    for (int r = 0; r < 4; ++r)
                        if (mt * 16 + quad * 4 + r > qloc) sc[st][mt][r] = -1e30f;
            }
        }
        #pragma unroll
        for (int st = 0; st < 2; ++st) {
            float mx = -1e30f;
            #pragma unroll
            for (int mt = 0; mt < 4; ++mt)
                #pragma unroll
                for (int r = 0; r < 4; ++r) mx = fmaxf(mx, sc[st][mt][r]);
            mx = fmaxf(mx, __shfl_xor(mx, 16));
            mx = fmaxf(mx, __shfl_xor(mx, 32));
            const float mn = fmaxf(m[st], mx * scale);
            const float f  = __expf(m[st] - mn);
            m[st] = mn;
            float rs = 0.f;
            #pragma unroll
            for (int mt = 0; mt < 4; ++mt)
                #pragma unroll
                for (int r = 0; r < 4; ++r) {
                    const float p = u2f(f2u(__expf(fmaf(sc[st][mt][r], scale, -mn))));
                    sc[st][mt][r] = p;          // bf16-rounded weight
                    rs += p;
                }
            rs += __shfl_xor(rs, 16);
            rs += __shfl_xor(rs, 32);
            l[st] = l[st] * f + rs;
            #pragma unroll
            for (int dm = 0; dm < 3; ++dm)
                #pragma unroll
                for (int r = 0; r < 4; ++r) acc[st][dm][r] *= f;
            // pack P to per-wave scratch: Pst[q=lr][key], key pairs -> u32
            short* Pst = Pw + st * 16 * 72;
            #pragma unroll
            for (int mt = 0; mt < 4; ++mt) {
                unsigned* pw = (unsigned*)&Pst[lr * 72 + mt * 16 + quad * 4];
                pw[0] = pk2(sc[st][mt][0], sc[st][mt][1]);
                pw[1] = pk2(sc[st][mt][2], sc[st][mt][3]);
            }
        }
        // B-frag read-back: lane holds P[q=lr][key = ks*32 + quad*8 + j]
        short8 pf[2][2];
        #pragma unroll
        for (int st = 0; st < 2; ++st) {
            const short* Pst = Pw + st * 16 * 72;
            pf[st][0] = *(const short8*)&Pst[lr * 72 + quad * 8];
            pf[st][1] = *(const short8*)&Pst[lr * 72 + 32 + quad * 8];
        }
        // O^T[d][q] += V^T·P^T : lane accumulates d = dm*16 + quad*4 + r, q = lr
        #pragma unroll
        for (int dm = 0; dm < 3; ++dm) {
            const short8 v0 = *(const short8*)&Vt[(dm * 16 + lr) * 72 + quad * 8];
            const short8 v1 = *(const short8*)&Vt[(dm * 16 + lr) * 72 + 32 + quad * 8];
            #pragma unroll
            for (int st = 0; st < 2; ++st) {
                acc[st][dm] = __builtin_amdgcn_mfma_f32_16x16x32_bf16(v0, pf[st][0], acc[st][dm], 0, 0, 0);
                acc[st][dm] = __builtin_amdgcn_mfma_f32_16x16x32_bf16(v1, pf[st][1], acc[st][dm], 0, 0, 0);
            }
        }
    }

    #pragma unroll
    for (int st = 0; st < 2; ++st) {
        const float inv = 1.0f / l[st];
        bf16* orow = ao + (size_t)(b * Tq + qg[st]) * QN + h * HDq;
        #pragma unroll
        for (int dm = 0; dm < 3; ++dm) {
            const unsigned w0 = pk2(acc[st][dm][0] * inv, acc[st][dm][1] * inv);
            const unsigned w1 = pk2(acc[st][dm][2] * inv, acc[st][dm][3] * inv);
            *(uint2*)(orow + dm * 16 + quad * 4) = make_uint2(w0, w1);
        }
    }
}

extern "C" void kernel_launch(void* const* d_in, const int* in_sizes, int n_in,
                              void* d_out, int out_size, void* d_ws, size_t ws_size,
                              hipStream_t stream) {
    const float* x   = (const float*)d_in[0];
    // d_in[1]: causal mask — static tril, applied analytically in mla_attn
    const float* Wq  = (const float*)d_in[2];
    const float* Wkv = (const float*)d_in[3];
    const float* wn  = (const float*)d_in[4];
    const float* Wk  = (const float*)d_in[5];
    const float* Wv  = (const float*)d_in[6];
    const float* Wo  = (const float*)d_in[7];
    float* out = (float*)d_out;

    const int M = Bq * Tq;                          // 4096
    // d_out staging (all dead before oproj's final write):
    //   [0        : 6.29M)   q bf16  [4096 x 768]
    //   [6.29M    : 10.49M)  xkv fp32 [4096 x 256]
    //   [10.49M   : 12.59M)  lat bf16 [4096 x 256]
    char* ob = (char*)d_out;
    bf16*  qws  = (bf16*)d_out;
    float* xkv  = (float*)(ob + 6291456);
    bf16*  latb = (bf16*)(ob + 10485760);
    // ws: k bf16 3.15M | v bf16 3.15M | ao bf16 6.29M
    bf16*  kws = (bf16*)d_ws;
    bf16*  vws = kws + (size_t)M * KVN;
    bf16*  aob = vws + (size_t)M * KVN;

    mla_qproj <<<dim3(M / 64, QN / 64), 256, 0, stream>>>(x, Wq, qws);
    mla_kvlat <<<dim3(M / 64, LATq / 64), 256, 0, stream>>>(x, Wkv, xkv);
    mla_kvrms <<<M / 4, 256, 0, stream>>>(xkv, wn, latb);
    mla_kvproj<<<dim3(M / 64, KVN / 64, 2), 256, 0, stream>>>(latb, Wk, Wv, kws, vws);
    mla_attn  <<<dim3(NHq, 32, Bq), 128, 0, stream>>>(qws, kws, vws, aob);
    mla_oproj <<<dim3(M / 64, Dq / 64), 256, 0, stream>>>(aob, Wo, out);
}

// Round 4
// 395.530 us; speedup vs baseline: 2.2360x; 1.0246x over previous
//
#include <hip/hip_runtime.h>
#include <hip/hip_bf16.h>

typedef __hip_bfloat16 bf16;
typedef __attribute__((ext_vector_type(8))) short short8;
typedef __attribute__((ext_vector_type(4))) float f32x4;

#define Bq   2
#define Tq   2048
#define Dq   2048
#define NHq  16
#define HDq  48
#define LATq 256
#define NLHq 8
#define QN   (NHq * HDq)    // 768
#define KVN  (NLHq * HDq)   // 384

__device__ __forceinline__ unsigned short f2u(float x) {
    __hip_bfloat16 h = __float2bfloat16(x);
    return *reinterpret_cast<unsigned short*>(&h);
}
__device__ __forceinline__ float u2f(unsigned short u) {
    return __uint_as_float((unsigned)u << 16);
}
__device__ __forceinline__ unsigned pk2(float a, float b) {
    return (unsigned)f2u(a) | ((unsigned)f2u(b) << 16);
}

// ==== MFMA GEMM: q = x @ Wq, [4096,2048]fp32 x [2048,768]fp32 -> bf16 ==========
// block 256 thr = 4 waves (2x2), tile 64x64, BK=32. A_lds[m][k] s40; B_lds[n][k]
// s40 with 16B-chunk XOR swizzle (chunk ^= (n>>2)&3) for conflict-light staging.
extern "C" __global__ void __launch_bounds__(256)
mla_qproj(const float* __restrict__ A, const float* __restrict__ B, bf16* __restrict__ C) {
    __shared__ short As[64 * 40];
    __shared__ short Bs[64 * 40];
    const int t  = threadIdx.x;
    const int m0 = blockIdx.x * 64;
    const int n0 = blockIdx.y * 64;
    const int w  = t >> 6;
    const int wm = (w & 1) * 32;
    const int wn = (w >> 1) * 32;
    const int l  = t & 63;
    const int lr = l & 15;
    const int quad = l >> 4;

    f32x4 acc[2][2];
    #pragma unroll
    for (int mi = 0; mi < 2; ++mi)
        #pragma unroll
        for (int ni = 0; ni < 2; ++ni) acc[mi][ni] = (f32x4){0.f, 0.f, 0.f, 0.f};

    int aoff[2], boff[2];
    #pragma unroll
    for (int mi = 0; mi < 2; ++mi) aoff[mi] = (wm + mi * 16 + lr) * 40 + quad * 8;
    #pragma unroll
    for (int ni = 0; ni < 2; ++ni) {
        const int n = wn + ni * 16 + lr;
        boff[ni] = n * 40 + (quad ^ ((n >> 2) & 3)) * 8;
    }

    for (int kt = 0; kt < Dq / 32; ++kt) {
        #pragma unroll
        for (int it = 0; it < 2; ++it) {              // A-tile 64x32: 512 float4
            const int idx = t + 256 * it;
            const int m = idx >> 3, k4 = idx & 7;
            const float4 a4 = *(const float4*)&A[(size_t)(m0 + m) * Dq + kt * 32 + k4 * 4];
            const unsigned u0 = f2u(a4.x) | ((unsigned)f2u(a4.y) << 16);
            const unsigned u1 = f2u(a4.z) | ((unsigned)f2u(a4.w) << 16);
            *(uint2*)&As[m * 40 + k4 * 4] = make_uint2(u0, u1);
        }
        #pragma unroll
        for (int it = 0; it < 2; ++it) {              // B-tile 32x64 transposed
            const int idx = t + 256 * it;
            const int k = idx >> 4, n4 = idx & 15;
            const float4 b4 = *(const float4*)&B[(size_t)(kt * 32 + k) * QN + n0 + n4 * 4];
            const float bb[4] = {b4.x, b4.y, b4.z, b4.w};
            #pragma unroll
            for (int j = 0; j < 4; ++j) {
                const int n = n4 * 4 + j;
                const int ch = (k >> 3) ^ ((n >> 2) & 3);
                Bs[n * 40 + ch * 8 + (k & 7)] = (short)f2u(bb[j]);
            }
        }
        __syncthreads();
        short8 af[2], bfr[2];
        #pragma unroll
        for (int mi = 0; mi < 2; ++mi) af[mi] = *(const short8*)&As[aoff[mi]];
        #pragma unroll
        for (int ni = 0; ni < 2; ++ni) bfr[ni] = *(const short8*)&Bs[boff[ni]];
        #pragma unroll
        for (int mi = 0; mi < 2; ++mi)
            #pragma unroll
            for (int ni = 0; ni < 2; ++ni)
                acc[mi][ni] = __builtin_amdgcn_mfma_f32_16x16x32_bf16(af[mi], bfr[ni], acc[mi][ni], 0, 0, 0);
        __syncthreads();
    }
    #pragma unroll
    for (int mi = 0; mi < 2; ++mi)
        #pragma unroll
        for (int ni = 0; ni < 2; ++ni) {
            const int col = n0 + wn + ni * 16 + lr;
            #pragma unroll
            for (int r = 0; r < 4; ++r) {
                const int row = m0 + wm + mi * 16 + quad * 4 + r;
                C[(size_t)row * QN + col] = __float2bfloat16(acc[mi][ni][r]);
            }
        }
}

// ==== MFMA GEMM: xkv = x @ Wkv, [4096,2048]fp32 x [2048,256]fp32 -> fp32 =======
extern "C" __global__ void __launch_bounds__(256)
mla_kvlat(const float* __restrict__ A, const float* __restrict__ B, float* __restrict__ C) {
    __shared__ short As[64 * 40];
    __shared__ short Bs[64 * 40];
    const int t  = threadIdx.x;
    const int m0 = blockIdx.x * 64;
    const int n0 = blockIdx.y * 64;
    const int w  = t >> 6;
    const int wm = (w & 1) * 32;
    const int wn = (w >> 1) * 32;
    const int l  = t & 63;
    const int lr = l & 15;
    const int quad = l >> 4;

    f32x4 acc[2][2];
    #pragma unroll
    for (int mi = 0; mi < 2; ++mi)
        #pragma unroll
        for (int ni = 0; ni < 2; ++ni) acc[mi][ni] = (f32x4){0.f, 0.f, 0.f, 0.f};

    int aoff[2], boff[2];
    #pragma unroll
    for (int mi = 0; mi < 2; ++mi) aoff[mi] = (wm + mi * 16 + lr) * 40 + quad * 8;
    #pragma unroll
    for (int ni = 0; ni < 2; ++ni) {
        const int n = wn + ni * 16 + lr;
        boff[ni] = n * 40 + (quad ^ ((n >> 2) & 3)) * 8;
    }

    for (int kt = 0; kt < Dq / 32; ++kt) {
        #pragma unroll
        for (int it = 0; it < 2; ++it) {              // A-tile 64x32: 512 float4
            const int idx = t + 256 * it;
            const int m = idx >> 3, k4 = idx & 7;
            const float4 a4 = *(const float4*)&A[(size_t)(m0 + m) * Dq + kt * 32 + k4 * 4];
            const unsigned u0 = f2u(a4.x) | ((unsigned)f2u(a4.y) << 16);
            const unsigned u1 = f2u(a4.z) | ((unsigned)f2u(a4.w) << 16);
            *(uint2*)&As[m * 40 + k4 * 4] = make_uint2(u0, u1);
        }
        #pragma unroll
        for (int it = 0; it < 2; ++it) {              // B-tile 32x64 transposed
            const int idx = t + 256 * it;
            const int k = idx >> 4, n4 = idx & 15;
            const float4 b4 = *(const float4*)&B[(size_t)(kt * 32 + k) * LATq + n0 + n4 * 4];
            const float bb[4] = {b4.x, b4.y, b4.z, b4.w};
            #pragma unroll
            for (int j = 0; j < 4; ++j) {
                const int n = n4 * 4 + j;
                const int ch = (k >> 3) ^ ((n >> 2) & 3);
                Bs[n * 40 + ch * 8 + (k & 7)] = (short)f2u(bb[j]);
            }
        }
        __syncthreads();
        short8 af[2], bfr[2];
        #pragma unroll
        for (int mi = 0; mi < 2; ++mi) af[mi] = *(const short8*)&As[aoff[mi]];
        #pragma unroll
        for (int ni = 0; ni < 2; ++ni) bfr[ni] = *(const short8*)&Bs[boff[ni]];
        #pragma unroll
        for (int mi = 0; mi < 2; ++mi)
            #pragma unroll
            for (int ni = 0; ni < 2; ++ni)
                acc[mi][ni] = __builtin_amdgcn_mfma_f32_16x16x32_bf16(af[mi], bfr[ni], acc[mi][ni], 0, 0, 0);
        __syncthreads();
    }
    #pragma unroll
    for (int mi = 0; mi < 2; ++mi)
        #pragma unroll
        for (int ni = 0; ni < 2; ++ni) {
            const int col = n0 + wn + ni * 16 + lr;
            #pragma unroll
            for (int r = 0; r < 4; ++r) {
                const int row = m0 + wm + mi * 16 + quad * 4 + r;
                C[(size_t)row * LATq + col] = acc[mi][ni][r];
            }
        }
}

// ---- lat = rmsnorm(xkv)*wn : [4096,256]fp32 -> bf16. 1 wave per row. ----------
extern "C" __global__ void __launch_bounds__(256)
mla_kvrms(const float* __restrict__ xkv, const float* __restrict__ wn,
          bf16* __restrict__ lat) {
    const int t = threadIdx.x;
    const int row = blockIdx.x * 4 + (t >> 6);
    const int lane = t & 63;
    const float4 v = *(const float4*)&xkv[(size_t)row * LATq + lane * 4];
    float ss = v.x * v.x + v.y * v.y + v.z * v.z + v.w * v.w;
    ss += __shfl_xor(ss, 1);  ss += __shfl_xor(ss, 2);  ss += __shfl_xor(ss, 4);
    ss += __shfl_xor(ss, 8);  ss += __shfl_xor(ss, 16); ss += __shfl_xor(ss, 32);
    const float rr = rsqrtf(ss * (1.0f / LATq) + 1e-5f);
    const float4 g = *(const float4*)&wn[lane * 4];
    const unsigned w0 = pk2(v.x * rr * g.x, v.y * rr * g.y);
    const unsigned w1 = pk2(v.z * rr * g.z, v.w * rr * g.w);
    *(uint2*)&lat[(size_t)row * LATq + lane * 4] = make_uint2(w0, w1);
}

// ==== MFMA GEMM: k/v = lat @ Wk|Wv, [4096,256]bf16 x [256,384]fp32 -> bf16 =====
extern "C" __global__ void __launch_bounds__(256)
mla_kvproj(const bf16* __restrict__ A, const float* __restrict__ Bk,
           const float* __restrict__ Bv, bf16* __restrict__ ko, bf16* __restrict__ vo) {
    __shared__ short As[64 * 40];
    __shared__ short Bs[64 * 40];
    const int t  = threadIdx.x;
    const int m0 = blockIdx.x * 64;
    const int n0 = blockIdx.y * 64;
    const float* B = blockIdx.z ? Bv : Bk;
    bf16* C = blockIdx.z ? vo : ko;
    const int w  = t >> 6;
    const int wm = (w & 1) * 32;
    const int wn = (w >> 1) * 32;
    const int l  = t & 63;
    const int lr = l & 15;
    const int quad = l >> 4;

    f32x4 acc[2][2];
    #pragma unroll
    for (int mi = 0; mi < 2; ++mi)
        #pragma unroll
        for (int ni = 0; ni < 2; ++ni) acc[mi][ni] = (f32x4){0.f, 0.f, 0.f, 0.f};

    int aoff[2], boff[2];
    #pragma unroll
    for (int mi = 0; mi < 2; ++mi) aoff[mi] = (wm + mi * 16 + lr) * 40 + quad * 8;
    #pragma unroll
    for (int ni = 0; ni < 2; ++ni) {
        const int n = wn + ni * 16 + lr;
        boff[ni] = n * 40 + (quad ^ ((n >> 2) & 3)) * 8;
    }

    for (int kt = 0; kt < LATq / 32; ++kt) {
        {                                             // A-tile 64x32 bf16: 256 uint4
            const int m = t >> 2, k8 = t & 3;
            *(uint4*)&As[m * 40 + k8 * 8] =
                *(const uint4*)&A[(size_t)(m0 + m) * LATq + kt * 32 + k8 * 8];
        }
        #pragma unroll
        for (int it = 0; it < 2; ++it) {              // B-tile 32x64 transposed
            const int idx = t + 256 * it;
            const int k = idx >> 4, n4 = idx & 15;
            const float4 b4 = *(const float4*)&B[(size_t)(kt * 32 + k) * KVN + n0 + n4 * 4];
            const float bb[4] = {b4.x, b4.y, b4.z, b4.w};
            #pragma unroll
            for (int j = 0; j < 4; ++j) {
                const int n = n4 * 4 + j;
                const int ch = (k >> 3) ^ ((n >> 2) & 3);
                Bs[n * 40 + ch * 8 + (k & 7)] = (short)f2u(bb[j]);
            }
        }
        __syncthreads();
        short8 af[2], bfr[2];
        #pragma unroll
        for (int mi = 0; mi < 2; ++mi) af[mi] = *(const short8*)&As[aoff[mi]];
        #pragma unroll
        for (int ni = 0; ni < 2; ++ni) bfr[ni] = *(const short8*)&Bs[boff[ni]];
        #pragma unroll
        for (int mi = 0; mi < 2; ++mi)
            #pragma unroll
            for (int ni = 0; ni < 2; ++ni)
                acc[mi][ni] = __builtin_amdgcn_mfma_f32_16x16x32_bf16(af[mi], bfr[ni], acc[mi][ni], 0, 0, 0);
        __syncthreads();
    }
    #pragma unroll
    for (int mi = 0; mi < 2; ++mi)
        #pragma unroll
        for (int ni = 0; ni < 2; ++ni) {
            const int col = n0 + wn + ni * 16 + lr;
            #pragma unroll
            for (int r = 0; r < 4; ++r) {
                const int row = m0 + wm + mi * 16 + quad * 4 + r;
                C[(size_t)row * KVN + col] = __float2bfloat16(acc[mi][ni][r]);
            }
        }
}

// ==== MFMA GEMM: out = ao @ Wo, [4096,768]bf16 x [768,2048]fp32 -> fp32 ========
extern "C" __global__ void __launch_bounds__(256)
mla_oproj(const bf16* __restrict__ A, const float* __restrict__ B, float* __restrict__ C) {
    __shared__ short As[64 * 40];
    __shared__ short Bs[64 * 40];
    const int t  = threadIdx.x;
    const int m0 = blockIdx.x * 64;
    const int n0 = blockIdx.y * 64;
    const int w  = t >> 6;
    const int wm = (w & 1) * 32;
    const int wn = (w >> 1) * 32;
    const int l  = t & 63;
    const int lr = l & 15;
    const int quad = l >> 4;

    f32x4 acc[2][2];
    #pragma unroll
    for (int mi = 0; mi < 2; ++mi)
        #pragma unroll
        for (int ni = 0; ni < 2; ++ni) acc[mi][ni] = (f32x4){0.f, 0.f, 0.f, 0.f};

    int aoff[2], boff[2];
    #pragma unroll
    for (int mi = 0; mi < 2; ++mi) aoff[mi] = (wm + mi * 16 + lr) * 40 + quad * 8;
    #pragma unroll
    for (int ni = 0; ni < 2; ++ni) {
        const int n = wn + ni * 16 + lr;
        boff[ni] = n * 40 + (quad ^ ((n >> 2) & 3)) * 8;
    }

    for (int kt = 0; kt < QN / 32; ++kt) {
        {                                             // A-tile 64x32 bf16: 256 uint4
            const int m = t >> 2, k8 = t & 3;
            *(uint4*)&As[m * 40 + k8 * 8] =
                *(const uint4*)&A[(size_t)(m0 + m) * QN + kt * 32 + k8 * 8];
        }
        #pragma unroll
        for (int it = 0; it < 2; ++it) {              // B-tile 32x64 transposed
            const int idx = t + 256 * it;
            const int k = idx >> 4, n4 = idx & 15;
            const float4 b4 = *(const float4*)&B[(size_t)(kt * 32 + k) * Dq + n0 + n4 * 4];
            const float bb[4] = {b4.x, b4.y, b4.z, b4.w};
            #pragma unroll
            for (int j = 0; j < 4; ++j) {
                const int n = n4 * 4 + j;
                const int ch = (k >> 3) ^ ((n >> 2) & 3);
                Bs[n * 40 + ch * 8 + (k & 7)] = (short)f2u(bb[j]);
            }
        }
        __syncthreads();
        short8 af[2], bfr[2];
        #pragma unroll
        for (int mi = 0; mi < 2; ++mi) af[mi] = *(const short8*)&As[aoff[mi]];
        #pragma unroll
        for (int ni = 0; ni < 2; ++ni) bfr[ni] = *(const short8*)&Bs[boff[ni]];
        #pragma unroll
        for (int mi = 0; mi < 2; ++mi)
            #pragma unroll
            for (int ni = 0; ni < 2; ++ni)
                acc[mi][ni] = __builtin_amdgcn_mfma_f32_16x16x32_bf16(af[mi], bfr[ni], acc[mi][ni], 0, 0, 0);
        __syncthreads();
    }
    #pragma unroll
    for (int mi = 0; mi < 2; ++mi)
        #pragma unroll
        for (int ni = 0; ni < 2; ++ni) {
            const int col = n0 + wn + ni * 16 + lr;
            #pragma unroll
            for (int r = 0; r < 4; ++r) {
                const int row = m0 + wm + mi * 16 + quad * 4 + r;
                C[(size_t)row * Dq + col] = acc[mi][ni][r];
            }
        }
}

// ==== MFMA flash attention, group-shared K/V ==================================
// Block = 256 thr (4 waves) = one (b, latent-group g): wave w owns head
// 2g+(w&1) and q-rows (w>>1)*32..+32 (2 subtiles of 16). K/V staged ONCE per
// group (was once per head). Register-prefetch double-buffer: per tile, issue
// next tile's K/V global loads into 3x uint4 regs, compute on buf[cur], write
// regs into buf[cur^1] -> ONE barrier per tile, global latency hidden under
// compute. Ks[2][64][48] stride 48 (96B, 16B-aligned); QK runs K=64 in 2 MFMAs
// with the second fragment exec-masked to quads 0-1 (cols 32-47) and zero
// elsewhere (matching zeroed Q frag halves). Vt[2][48][72] = V transposed at
// staging. Ps per-wave scratch for the P C-layout -> B-frag round trip; p is
// bf16-rounded BEFORE the row-sum so numerator/denominator match.
// Balance: grid (8 g, 32 qy, 2 b) = 512 blocks = 2/CU; qt(b=0) = pairing,
// qt(b=1) = 31 - qt(b=0), so co-resident pairs (i, i+256) sum to 33 tiles.
extern "C" __global__ void __launch_bounds__(256)
mla_attn(const bf16* __restrict__ q, const bf16* __restrict__ kk,
         const bf16* __restrict__ vv, bf16* __restrict__ ao) {
    __shared__ __align__(16) short Ks[2][64 * 48];
    __shared__ __align__(16) short Vt[2][48 * 72];
    __shared__ __align__(16) short Ps[4][2 * 16 * 72];
    const int t    = threadIdx.x;
    const int g    = blockIdx.x;
    const int qy   = blockIdx.y;
    const int b    = blockIdx.z;
    const int qt0  = (qy < 16) ? (qy << 1) : (63 - (qy << 1));
    const int qt   = b ? (31 - qt0) : qt0;
    const int w    = t >> 6;
    const int lane = t & 63;
    const int lr   = t & 15;
    const int quad = (t >> 4) & 3;
    const int hh   = w & 1;
    const int rh   = w >> 1;
    const int h    = g * 2 + hh;
    const int Q0   = qt * 64;
    const float scale = 0.14433756729740643f;   // 1/sqrt(48)
    const short8 z8 = {0, 0, 0, 0, 0, 0, 0, 0};

    // Q fragments (B-operand): lane holds Q[q = lr][d = ks*32 + quad*8 + j]
    short8 qf[2][2];
    int qg[2];
    #pragma unroll
    for (int st = 0; st < 2; ++st) {
        qg[st] = Q0 + rh * 32 + st * 16 + lr;
        const bf16* qr = q + (size_t)(b * Tq + qg[st]) * QN + h * HDq;
        qf[st][0] = *(const short8*)(qr + quad * 8);
        const short8 q1 = *(const short8*)(qr + 32 + (quad & 1) * 8);
        qf[st][1] = (quad < 2) ? q1 : z8;
    }

    const bf16* kb = kk + (size_t)b * Tq * KVN + g * HDq;
    const bf16* vb = vv + (size_t)b * Tq * KVN + g * HDq;

    float m[2] = {-1e30f, -1e30f}, l[2] = {0.f, 0.f};
    f32x4 acc[2][3];
    #pragma unroll
    for (int st = 0; st < 2; ++st)
        #pragma unroll
        for (int dm = 0; dm < 3; ++dm) acc[st][dm] = (f32x4){0.f, 0.f, 0.f, 0.f};

    short* Pw = &Ps[w][0];
    uint4 pre[3];

    // staging roles: waves 0,1 -> K (384 uint4 tasks, row=idx/6 ch=idx%6);
    // waves 2,3 -> V^T (384 tasks: key-pair kp=idx&31, half-chunk hc=idx>>5).
    auto issue = [&](int tl) {
        #pragma unroll
        for (int r = 0; r < 3; ++r) {
            if (w < 2) {
                const int idx = (w * 3 + r) * 64 + lane;
                const int row = idx / 6, ch = idx - row * 6;
                pre[r] = *(const uint4*)(kb + (size_t)(tl * 64 + row) * KVN + ch * 8);
            } else {
                const int idx = ((w - 2) * 3 + r) * 64 + lane;
                const int kp = idx & 31, hc = idx >> 5;
                const bf16* src = vb + (size_t)(tl * 64 + 2 * kp) * KVN + hc * 4;
                const uint2 a2 = *(const uint2*)src;
                const uint2 b2 = *(const uint2*)(src + KVN);
                pre[r].x = a2.x; pre[r].y = a2.y; pre[r].z = b2.x; pre[r].w = b2.y;
            }
        }
    };
    auto lwrite = [&](int bb) {
        #pragma unroll
        for (int r = 0; r < 3; ++r) {
            if (w < 2) {
                const int idx = (w * 3 + r) * 64 + lane;
                const int row = idx / 6, ch = idx - row * 6;
                *(uint4*)&Ks[bb][row * 48 + ch * 8] = pre[r];
            } else {
                const int idx = ((w - 2) * 3 + r) * 64 + lane;
                const int kp = idx & 31, hc = idx >> 5;
                const unsigned short* u = (const unsigned short*)&pre[r];
                #pragma unroll
                for (int j = 0; j < 4; ++j)
                    *(unsigned*)&Vt[bb][(hc * 4 + j) * 72 + 2 * kp] =
                        (unsigned)u[j] | ((unsigned)u[4 + j] << 16);
            }
        }
    };

    issue(0);
    lwrite(0);
    __syncthreads();
    int cur = 0;

    for (int tl = 0; tl <= qt; ++tl) {
        const bool pref = (tl < qt);
        if (pref) issue(tl + 1);

        // S^T[key][q] = K·Q^T : lane holds key = mt*16 + quad*4 + r, q = lr
        f32x4 sc[2][4];
        #pragma unroll
        for (int mt = 0; mt < 4; ++mt) {
            const short8 k0 = *(const short8*)&Ks[cur][(mt * 16 + lr) * 48 + quad * 8];
            const short8 k1v = *(const short8*)&Ks[cur][(mt * 16 + lr) * 48 + 32 + (quad & 1) * 8];
            const short8 k1 = (quad < 2) ? k1v : z8;
            #pragma unroll
            for (int st = 0; st < 2; ++st) {
                f32x4 s = (f32x4){0.f, 0.f, 0.f, 0.f};
                s = __builtin_amdgcn_mfma_f32_16x16x32_bf16(k0, qf[st][0], s, 0, 0, 0);
                s = __builtin_amdgcn_mfma_f32_16x16x32_bf16(k1, qf[st][1], s, 0, 0, 0);
                sc[st][mt] = s;
            }
        }
        if (tl == qt) {                         // diagonal tile: mask key > q
            #pragma unroll
            for (int st = 0; st < 2; ++st) {
                const int qloc = rh * 32 + st * 16 + lr;
                #pragma unroll
                for (int mt = 0; mt < 4; ++mt)
                    #pragma unroll
                    for (int r = 0; r < 4; ++r)
                        if (mt * 16 + quad * 4 + r > qloc) sc[st][mt][r] = -1e30f;
            }
        }
        #pragma unroll
        for (int st = 0; st < 2; ++st) {
            float mx = -1e30f;
            #pragma unroll
            for (int mt = 0; mt < 4; ++mt)
                #pragma unroll
                for (int r = 0; r < 4; ++r) mx = fmaxf(mx, sc[st][mt][r]);
            mx = fmaxf(mx, __shfl_xor(mx, 16));
            mx = fmaxf(mx, __shfl_xor(mx, 32));
            const float mn = fmaxf(m[st], mx * scale);
            const float f  = __expf(m[st] - mn);
            m[st] = mn;
            float rs = 0.f;
            #pragma unroll
            for (int mt = 0; mt < 4; ++mt)
                #pragma unroll
                for (int r = 0; r < 4; ++r) {
                    const float p = u2f(f2u(__expf(fmaf(sc[st][mt][r], scale, -mn))));
                    sc[st][mt][r] = p;          // bf16-rounded weight
                    rs += p;
                }
            rs += __shfl_xor(rs, 16);
            rs += __shfl_xor(rs, 32);
            l[st] = l[st] * f + rs;
            #pragma unroll
            for (int dm = 0; dm < 3; ++dm)
                #pragma unroll
                for (int r = 0; r < 4; ++r) acc[st][dm][r] *= f;
            // pack P to per-wave scratch: Pst[q=lr][key], key pairs -> u32
            short* Pst = Pw + st * 16 * 72;
            #pragma unroll
            for (int mt = 0; mt < 4; ++mt) {
                unsigned* pw = (unsigned*)&Pst[lr * 72 + mt * 16 + quad * 4];
                pw[0] = pk2(sc[st][mt][0], sc[st][mt][1]);
                pw[1] = pk2(sc[st][mt][2], sc[st][mt][3]);
            }
        }
        // B-frag read-back: lane holds P[q=lr][key = ks*32 + quad*8 + j]
        short8 pf[2][2];
        #pragma unroll
        for (int st = 0; st < 2; ++st) {
            const short* Pst = Pw + st * 16 * 72;
            pf[st][0] = *(const short8*)&Pst[lr * 72 + quad * 8];
            pf[st][1] = *(const short8*)&Pst[lr * 72 + 32 + quad * 8];
        }
        // O^T[d][q] += V^T·P^T : lane accumulates d = dm*16 + quad*4 + r, q = lr
        #pragma unroll
        for (int dm = 0; dm < 3; ++dm) {
            const short8 v0 = *(const short8*)&Vt[cur][(dm * 16 + lr) * 72 + quad * 8];
            const short8 v1 = *(const short8*)&Vt[cur][(dm * 16 + lr) * 72 + 32 + quad * 8];
            #pragma unroll
            for (int st = 0; st < 2; ++st) {
                acc[st][dm] = __builtin_amdgcn_mfma_f32_16x16x32_bf16(v0, pf[st][0], acc[st][dm], 0, 0, 0);
                acc[st][dm] = __builtin_amdgcn_mfma_f32_16x16x32_bf16(v1, pf[st][1], acc[st][dm], 0, 0, 0);
            }
        }

        if (pref) lwrite(cur ^ 1);              // overlapped with other waves' compute
        __syncthreads();
        cur ^= 1;
    }

    #pragma unroll
    for (int st = 0; st < 2; ++st) {
        const float inv = 1.0f / l[st];
        bf16* orow = ao + (size_t)(b * Tq + qg[st]) * QN + h * HDq;
        #pragma unroll
        for (int dm = 0; dm < 3; ++dm) {
            const unsigned w0 = pk2(acc[st][dm][0] * inv, acc[st][dm][1] * inv);
            const unsigned w1 = pk2(acc[st][dm][2] * inv, acc[st][dm][3] * inv);
            *(uint2*)(orow + dm * 16 + quad * 4) = make_uint2(w0, w1);
        }
    }
}

extern "C" void kernel_launch(void* const* d_in, const int* in_sizes, int n_in,
                              void* d_out, int out_size, void* d_ws, size_t ws_size,
                              hipStream_t stream) {
    const float* x   = (const float*)d_in[0];
    // d_in[1]: causal mask — static tril, applied analytically in mla_attn
    const float* Wq  = (const float*)d_in[2];
    const float* Wkv = (const float*)d_in[3];
    const float* wn  = (const float*)d_in[4];
    const float* Wk  = (const float*)d_in[5];
    const float* Wv  = (const float*)d_in[6];
    const float* Wo  = (const float*)d_in[7];
    float* out = (float*)d_out;

    const int M = Bq * Tq;                          // 4096
    // d_out staging (all dead before oproj's final write):
    //   [0        : 6.29M)   q bf16  [4096 x 768]
    //   [6.29M    : 10.49M)  xkv fp32 [4096 x 256]
    //   [10.49M   : 12.59M)  lat bf16 [4096 x 256]
    char* ob = (char*)d_out;
    bf16*  qws  = (bf16*)d_out;
    float* xkv  = (float*)(ob + 6291456);
    bf16*  latb = (bf16*)(ob + 10485760);
    // ws: k bf16 3.15M | v bf16 3.15M | ao bf16 6.29M
    bf16*  kws = (bf16*)d_ws;
    bf16*  vws = kws + (size_t)M * KVN;
    bf16*  aob = vws + (size_t)M * KVN;

    mla_qproj <<<dim3(M / 64, QN / 64), 256, 0, stream>>>(x, Wq, qws);
    mla_kvlat <<<dim3(M / 64, LATq / 64), 256, 0, stream>>>(x, Wkv, xkv);
    mla_kvrms <<<M / 4, 256, 0, stream>>>(xkv, wn, latb);
    mla_kvproj<<<dim3(M / 64, KVN / 64, 2), 256, 0, stream>>>(latb, Wk, Wv, kws, vws);
    mla_attn  <<<dim3(NLHq, 32, Bq), 256, 0, stream>>>(qws, kws, vws, aob);
    mla_oproj <<<dim3(M / 64, Dq / 64), 256, 0, stream>>>(aob, Wo, out);
}

// Round 6
// 320.859 us; speedup vs baseline: 2.7564x; 1.2327x over previous
//
#include <hip/hip_runtime.h>
#include <hip/hip_bf16.h>

typedef __hip_bfloat16 bf16;
typedef __attribute__((ext_vector_type(8))) short short8;
typedef __attribute__((ext_vector_type(4))) float f32x4;

#define Bq   2
#define Tq   2048
#define Dq   2048
#define NHq  16
#define HDq  48
#define LATq 256
#define NLHq 8
#define QN   (NHq * HDq)    // 768
#define KVN  (NLHq * HDq)   // 384

__device__ __forceinline__ unsigned short f2u(float x) {
    __hip_bfloat16 h = __float2bfloat16(x);
    return *reinterpret_cast<unsigned short*>(&h);
}
__device__ __forceinline__ float u2f(unsigned short u) {
    return __uint_as_float((unsigned)u << 16);
}
__device__ __forceinline__ unsigned pk2(float a, float b) {
    return (unsigned)f2u(a) | ((unsigned)f2u(b) << 16);
}
__device__ __forceinline__ void cstore(bf16* C, size_t i, float v) { C[i] = __float2bfloat16(v); }
__device__ __forceinline__ void cstore(float* C, size_t i, float v) { C[i] = v; }

// ---- x fp32 -> bf16, 8 elems/thread ------------------------------------------
__global__ void __launch_bounds__(256)
cvt_x(const float* __restrict__ in, bf16* __restrict__ out) {
    const size_t i = ((size_t)blockIdx.x * 256 + threadIdx.x) * 8;
    const float4 a = *(const float4*)&in[i];
    const float4 b = *(const float4*)&in[i + 4];
    uint4 u;
    u.x = pk2(a.x, a.y); u.y = pk2(a.z, a.w);
    u.z = pk2(b.x, b.y); u.w = pk2(b.z, b.w);
    *(uint4*)&out[i] = u;
}

// ---- W fp32 [K][N] -> WT bf16 [N][K], 32x32 LDS tiles -------------------------
__global__ void __launch_bounds__(256)
tr_w(const float* __restrict__ W, bf16* __restrict__ WT, int K, int N) {
    __shared__ float ts[32][33];
    const int n0 = blockIdx.x * 32, k0 = blockIdx.y * 32;
    const int t = threadIdx.x;
    const int r = t >> 3, c4 = (t & 7) * 4;
    const float4 v = *(const float4*)&W[(size_t)(k0 + r) * N + n0 + c4];
    ts[r][c4] = v.x; ts[r][c4 + 1] = v.y; ts[r][c4 + 2] = v.z; ts[r][c4 + 3] = v.w;
    __syncthreads();
    const unsigned u0 = pk2(ts[c4][r], ts[c4 + 1][r]);
    const unsigned u1 = pk2(ts[c4 + 2][r], ts[c4 + 3][r]);
    *(uint2*)&WT[(size_t)(n0 + r) * K + k0 + c4] = make_uint2(u0, u1);
}

// ==== bf16 GEMM, 128x64 tile: C[M][NC] = A[M][K] x BT[NC][K] ===================
// 256 thr / 4 waves (2 wm x 2 wn); wave = 64x32 out = 4x2 16x16 frags, BK=32.
// Pure uint4 staging (no cvt in loop). s40 LDS rows: 2-way banks on write,
// benign on b128 frag reads (same pattern as verified 64^2 kernel).
template<typename CT>
__global__ void __launch_bounds__(256)
gemm_bt128(const bf16* __restrict__ A, const bf16* __restrict__ BT,
           CT* __restrict__ C, int K, int NC) {
    __shared__ short As[128 * 40];
    __shared__ short Bs[64 * 40];
    const int t  = threadIdx.x;
    const int m0 = blockIdx.x * 128;
    const int n0 = blockIdx.y * 64;
    const int w  = t >> 6;
    const int wm = (w & 1) * 64;
    const int wn = (w >> 1) * 32;
    const int lr = t & 15;
    const int quad = (t >> 4) & 3;
    const int am = t >> 2, ac = t & 3;          // staging: row am, 16B chunk ac

    f32x4 acc[4][2];
    #pragma unroll
    for (int mi = 0; mi < 4; ++mi)
        #pragma unroll
        for (int ni = 0; ni < 2; ++ni) acc[mi][ni] = (f32x4){0.f, 0.f, 0.f, 0.f};

    int aoff[4], boff[2];
    #pragma unroll
    for (int mi = 0; mi < 4; ++mi) aoff[mi] = (wm + mi * 16 + lr) * 40 + quad * 8;
    #pragma unroll
    for (int ni = 0; ni < 2; ++ni) boff[ni] = (wn + ni * 16 + lr) * 40 + quad * 8;

    for (int kt = 0; kt < K / 32; ++kt) {
        const int kb = kt * 32 + ac * 8;
        *(uint4*)&As[am * 40 + ac * 8] = *(const uint4*)&A[(size_t)(m0 + am) * K + kb];
        *(uint4*)&As[(am + 64) * 40 + ac * 8] = *(const uint4*)&A[(size_t)(m0 + am + 64) * K + kb];
        *(uint4*)&Bs[am * 40 + ac * 8] = *(const uint4*)&BT[(size_t)(n0 + am) * K + kb];
        __syncthreads();
        short8 af[4], bfr[2];
        #pragma unroll
        for (int mi = 0; mi < 4; ++mi) af[mi] = *(const short8*)&As[aoff[mi]];
        #pragma unroll
        for (int ni = 0; ni < 2; ++ni) bfr[ni] = *(const short8*)&Bs[boff[ni]];
        #pragma unroll
        for (int mi = 0; mi < 4; ++mi)
            #pragma unroll
            for (int ni = 0; ni < 2; ++ni)
                acc[mi][ni] = __builtin_amdgcn_mfma_f32_16x16x32_bf16(af[mi], bfr[ni], acc[mi][ni], 0, 0, 0);
        __syncthreads();
    }
    #pragma unroll
    for (int mi = 0; mi < 4; ++mi)
        #pragma unroll
        for (int ni = 0; ni < 2; ++ni) {
            const int col = n0 + wn + ni * 16 + lr;
            #pragma unroll
            for (int r = 0; r < 4; ++r) {
                const int row = m0 + wm + mi * 16 + quad * 4 + r;
                cstore(C, (size_t)row * NC + col, acc[mi][ni][r]);
            }
        }
}

// ==== bf16 GEMM, 64x64 tile (small-N shapes: kvlat N=256, kvproj N=384) ========
template<typename CT>
__global__ void __launch_bounds__(256)
gemm_bt64(const bf16* __restrict__ A, const bf16* __restrict__ BT,
          CT* __restrict__ C, int K, int NC) {
    __shared__ short As[64 * 40];
    __shared__ short Bs[64 * 40];
    const int t  = threadIdx.x;
    const int m0 = blockIdx.x * 64;
    const int n0 = blockIdx.y * 64;
    const int w  = t >> 6;
    const int wm = (w & 1) * 32;
    const int wn = (w >> 1) * 32;
    const int lr = t & 15;
    const int quad = (t >> 4) & 3;
    const int am = t >> 2, ac = t & 3;

    f32x4 acc[2][2];
    #pragma unroll
    for (int mi = 0; mi < 2; ++mi)
        #pragma unroll
        for (int ni = 0; ni < 2; ++ni) acc[mi][ni] = (f32x4){0.f, 0.f, 0.f, 0.f};

    int aoff[2], boff[2];
    #pragma unroll
    for (int mi = 0; mi < 2; ++mi) aoff[mi] = (wm + mi * 16 + lr) * 40 + quad * 8;
    #pragma unroll
    for (int ni = 0; ni < 2; ++ni) boff[ni] = (wn + ni * 16 + lr) * 40 + quad * 8;

    for (int kt = 0; kt < K / 32; ++kt) {
        const int kb = kt * 32 + ac * 8;
        *(uint4*)&As[am * 40 + ac * 8] = *(const uint4*)&A[(size_t)(m0 + am) * K + kb];
        *(uint4*)&Bs[am * 40 + ac * 8] = *(const uint4*)&BT[(size_t)(n0 + am) * K + kb];
        __syncthreads();
        short8 af[2], bfr[2];
        #pragma unroll
        for (int mi = 0; mi < 2; ++mi) af[mi] = *(const short8*)&As[aoff[mi]];
        #pragma unroll
        for (int ni = 0; ni < 2; ++ni) bfr[ni] = *(const short8*)&Bs[boff[ni]];
        #pragma unroll
        for (int mi = 0; mi < 2; ++mi)
            #pragma unroll
            for (int ni = 0; ni < 2; ++ni)
                acc[mi][ni] = __builtin_amdgcn_mfma_f32_16x16x32_bf16(af[mi], bfr[ni], acc[mi][ni], 0, 0, 0);
        __syncthreads();
    }
    #pragma unroll
    for (int mi = 0; mi < 2; ++mi)
        #pragma unroll
        for (int ni = 0; ni < 2; ++ni) {
            const int col = n0 + wn + ni * 16 + lr;
            #pragma unroll
            for (int r = 0; r < 4; ++r) {
                const int row = m0 + wm + mi * 16 + quad * 4 + r;
                cstore(C, (size_t)row * NC + col, acc[mi][ni][r]);
            }
        }
}

// ---- lat = rmsnorm(xkv)*wn : [4096,256]fp32 -> bf16. 1 wave per row. ----------
__global__ void __launch_bounds__(256)
mla_kvrms(const float* __restrict__ xkv, const float* __restrict__ wn,
          bf16* __restrict__ lat) {
    const int t = threadIdx.x;
    const int row = blockIdx.x * 4 + (t >> 6);
    const int lane = t & 63;
    const float4 v = *(const float4*)&xkv[(size_t)row * LATq + lane * 4];
    float ss = v.x * v.x + v.y * v.y + v.z * v.z + v.w * v.w;
    ss += __shfl_xor(ss, 1);  ss += __shfl_xor(ss, 2);  ss += __shfl_xor(ss, 4);
    ss += __shfl_xor(ss, 8);  ss += __shfl_xor(ss, 16); ss += __shfl_xor(ss, 32);
    const float rr = rsqrtf(ss * (1.0f / LATq) + 1e-5f);
    const float4 g = *(const float4*)&wn[lane * 4];
    const unsigned w0 = pk2(v.x * rr * g.x, v.y * rr * g.y);
    const unsigned w1 = pk2(v.z * rr * g.z, v.w * rr * g.w);
    *(uint2*)&lat[(size_t)row * LATq + lane * 4] = make_uint2(w0, w1);
}

// ==== MFMA flash attention, group-shared K/V (unchanged from R4) ==============
// Block = 256 thr (4 waves) = one (b, latent-group g): wave w owns head
// 2g+(w&1) and q-rows (w>>1)*32..+32. K/V staged once per group; register-
// prefetch double-buffer, one barrier per tile. Ks stride 48, Vt stride 72,
// Ps per-wave scratch for the P C-layout -> B-frag round trip.
__global__ void __launch_bounds__(256)
mla_attn(const bf16* __restrict__ q, const bf16* __restrict__ kk,
         const bf16* __restrict__ vv, bf16* __restrict__ ao) {
    __shared__ __align__(16) short Ks[2][64 * 48];
    __shared__ __align__(16) short Vt[2][48 * 72];
    __shared__ __align__(16) short Ps[4][2 * 16 * 72];
    const int t    = threadIdx.x;
    const int g    = blockIdx.x;
    const int qy   = blockIdx.y;
    const int b    = blockIdx.z;
    const int qt0  = (qy < 16) ? (qy << 1) : (63 - (qy << 1));
    const int qt   = b ? (31 - qt0) : qt0;
    const int w    = t >> 6;
    const int lane = t & 63;
    const int lr   = t & 15;
    const int quad = (t >> 4) & 3;
    const int hh   = w & 1;
    const int rh   = w >> 1;
    const int h    = g * 2 + hh;
    const int Q0   = qt * 64;
    const float scale = 0.14433756729740643f;   // 1/sqrt(48)
    const short8 z8 = {0, 0, 0, 0, 0, 0, 0, 0};

    short8 qf[2][2];
    int qg[2];
    #pragma unroll
    for (int st = 0; st < 2; ++st) {
        qg[st] = Q0 + rh * 32 + st * 16 + lr;
        const bf16* qr = q + (size_t)(b * Tq + qg[st]) * QN + h * HDq;
        qf[st][0] = *(const short8*)(qr + quad * 8);
        const short8 q1 = *(const short8*)(qr + 32 + (quad & 1) * 8);
        qf[st][1] = (quad < 2) ? q1 : z8;
    }

    const bf16* kb = kk + (size_t)b * Tq * KVN + g * HDq;
    const bf16* vb = vv + (size_t)b * Tq * KVN + g * HDq;

    float m[2] = {-1e30f, -1e30f}, l[2] = {0.f, 0.f};
    f32x4 acc[2][3];
    #pragma unroll
    for (int st = 0; st < 2; ++st)
        #pragma unroll
        for (int dm = 0; dm < 3; ++dm) acc[st][dm] = (f32x4){0.f, 0.f, 0.f, 0.f};

    short* Pw = &Ps[w][0];
    uint4 pre[3];

    auto issue = [&](int tl) {
        #pragma unroll
        for (int r = 0; r < 3; ++r) {
            if (w < 2) {
                const int idx = (w * 3 + r) * 64 + lane;
                const int row = idx / 6, ch = idx - row * 6;
                pre[r] = *(const uint4*)(kb + (size_t)(tl * 64 + row) * KVN + ch * 8);
            } else {
                const int idx = ((w - 2) * 3 + r) * 64 + lane;
                const int kp = idx & 31, hc = idx >> 5;
                const bf16* src = vb + (size_t)(tl * 64 + 2 * kp) * KVN + hc * 4;
                const uint2 a2 = *(const uint2*)src;
                const uint2 b2 = *(const uint2*)(src + KVN);
                pre[r].x = a2.x; pre[r].y = a2.y; pre[r].z = b2.x; pre[r].w = b2.y;
            }
        }
    };
    auto lwrite = [&](int bb) {
        #pragma unroll
        for (int r = 0; r < 3; ++r) {
            if (w < 2) {
                const int idx = (w * 3 + r) * 64 + lane;
                const int row = idx / 6, ch = idx - row * 6;
                *(uint4*)&Ks[bb][row * 48 + ch * 8] = pre[r];
            } else {
                const int idx = ((w - 2) * 3 + r) * 64 + lane;
                const int kp = idx & 31, hc = idx >> 5;
                const unsigned short* u = (const unsigned short*)&pre[r];
                #pragma unroll
                for (int j = 0; j < 4; ++j)
                    *(unsigned*)&Vt[bb][(hc * 4 + j) * 72 + 2 * kp] =
                        (unsigned)u[j] | ((unsigned)u[4 + j] << 16);
            }
        }
    };

    issue(0);
    lwrite(0);
    __syncthreads();
    int cur = 0;

    for (int tl = 0; tl <= qt; ++tl) {
        const bool pref = (tl < qt);
        if (pref) issue(tl + 1);

        f32x4 sc[2][4];
        #pragma unroll
        for (int mt = 0; mt < 4; ++mt) {
            const short8 k0 = *(const short8*)&Ks[cur][(mt * 16 + lr) * 48 + quad * 8];
            const short8 k1v = *(const short8*)&Ks[cur][(mt * 16 + lr) * 48 + 32 + (quad & 1) * 8];
            const short8 k1 = (quad < 2) ? k1v : z8;
            #pragma unroll
            for (int st = 0; st < 2; ++st) {
                f32x4 s = (f32x4){0.f, 0.f, 0.f, 0.f};
                s = __builtin_amdgcn_mfma_f32_16x16x32_bf16(k0, qf[st][0], s, 0, 0, 0);
                s = __builtin_amdgcn_mfma_f32_16x16x32_bf16(k1, qf[st][1], s, 0, 0, 0);
                sc[st][mt] = s;
            }
        }
        if (tl == qt) {
            #pragma unroll
            for (int st = 0; st < 2; ++st) {
                const int qloc = rh * 32 + st * 16 + lr;
                #pragma unroll
                for (int mt = 0; mt < 4; ++mt)
                    #pragma unroll
                    for (int r = 0; r < 4; ++r)
                        if (mt * 16 + quad * 4 + r > qloc) sc[st][mt][r] = -1e30f;
            }
        }
        #pragma unroll
        for (int st = 0; st < 2; ++st) {
            float mx = -1e30f;
            #pragma unroll
            for (int mt = 0; mt < 4; ++mt)
                #pragma unroll
                for (int r = 0; r < 4; ++r) mx = fmaxf(mx, sc[st][mt][r]);
            mx = fmaxf(mx, __shfl_xor(mx, 16));
            mx = fmaxf(mx, __shfl_xor(mx, 32));
            const float mn = fmaxf(m[st], mx * scale);
            const float f  = __expf(m[st] - mn);
            m[st] = mn;
            float rs = 0.f;
            #pragma unroll
            for (int mt = 0; mt < 4; ++mt)
                #pragma unroll
                for (int r = 0; r < 4; ++r) {
                    const float p = u2f(f2u(__expf(fmaf(sc[st][mt][r], scale, -mn))));
                    sc[st][mt][r] = p;
                    rs += p;
                }
            rs += __shfl_xor(rs, 16);
            rs += __shfl_xor(rs, 32);
            l[st] = l[st] * f + rs;
            #pragma unroll
            for (int dm = 0; dm < 3; ++dm)
                #pragma unroll
                for (int r = 0; r < 4; ++r) acc[st][dm][r] *= f;
            short* Pst = Pw + st * 16 * 72;
            #pragma unroll
            for (int mt = 0; mt < 4; ++mt) {
                unsigned* pw = (unsigned*)&Pst[lr * 72 + mt * 16 + quad * 4];
                pw[0] = pk2(sc[st][mt][0], sc[st][mt][1]);
                pw[1] = pk2(sc[st][mt][2], sc[st][mt][3]);
            }
        }
        short8 pf[2][2];
        #pragma unroll
        for (int st = 0; st < 2; ++st) {
            const short* Pst = Pw + st * 16 * 72;
            pf[st][0] = *(const short8*)&Pst[lr * 72 + quad * 8];
            pf[st][1] = *(const short8*)&Pst[lr * 72 + 32 + quad * 8];
        }
        #pragma unroll
        for (int dm = 0; dm < 3; ++dm) {
            const short8 v0 = *(const short8*)&Vt[cur][(dm * 16 + lr) * 72 + quad * 8];
            const short8 v1 = *(const short8*)&Vt[cur][(dm * 16 + lr) * 72 + 32 + quad * 8];
            #pragma unroll
            for (int st = 0; st < 2; ++st) {
                acc[st][dm] = __builtin_amdgcn_mfma_f32_16x16x32_bf16(v0, pf[st][0], acc[st][dm], 0, 0, 0);
                acc[st][dm] = __builtin_amdgcn_mfma_f32_16x16x32_bf16(v1, pf[st][1], acc[st][dm], 0, 0, 0);
            }
        }

        if (pref) lwrite(cur ^ 1);
        __syncthreads();
        cur ^= 1;
    }

    #pragma unroll
    for (int st = 0; st < 2; ++st) {
        const float inv = 1.0f / l[st];
        bf16* orow = ao + (size_t)(b * Tq + qg[st]) * QN + h * HDq;
        #pragma unroll
        for (int dm = 0; dm < 3; ++dm) {
            const unsigned w0 = pk2(acc[st][dm][0] * inv, acc[st][dm][1] * inv);
            const unsigned w1 = pk2(acc[st][dm][2] * inv, acc[st][dm][3] * inv);
            *(uint2*)(orow + dm * 16 + quad * 4) = make_uint2(w0, w1);
        }
    }
}

extern "C" void kernel_launch(void* const* d_in, const int* in_sizes, int n_in,
                              void* d_out, int out_size, void* d_ws, size_t ws_size,
                              hipStream_t stream) {
    const float* x   = (const float*)d_in[0];
    // d_in[1]: causal mask — static tril, applied analytically in mla_attn
    const float* Wq  = (const float*)d_in[2];
    const float* Wkv = (const float*)d_in[3];
    const float* wn  = (const float*)d_in[4];
    const float* Wk  = (const float*)d_in[5];
    const float* Wv  = (const float*)d_in[6];
    const float* Wo  = (const float*)d_in[7];
    float* out = (float*)d_out;

    const int M = Bq * Tq;                          // 4096
    // d_out staging (all dead before oproj's final write; exactly 33,554,432 B):
    //   [0        : 16.78M)  xb   bf16 [4096 x 2048]   (dead after kvlat)
    //   [16.78M   : 23.07M)  q    bf16 [4096 x 768]
    //   [23.07M   : 27.26M)  xkv  fp32 [4096 x 256]
    //   [27.26M   : 29.36M)  lat  bf16 [4096 x 256]
    //   [29.36M   : 32.51M)  WqT  bf16 [768 x 2048]
    //   [32.51M   : 33.55M)  WkvT bf16 [256 x 2048]
    //   WkT/WvT reuse the xb region after kvlat (stream-ordered).
    char* ob = (char*)d_out;
    bf16*  xb   = (bf16*)ob;
    bf16*  qws  = (bf16*)(ob + 16777216);
    float* xkv  = (float*)(ob + 23068672);
    bf16*  latb = (bf16*)(ob + 27262976);
    bf16*  WqT  = (bf16*)(ob + 29360128);
    bf16*  WkvT = (bf16*)(ob + 32505856);
    bf16*  WkT  = (bf16*)ob;                        // after kvlat
    bf16*  WvT  = (bf16*)(ob + 393216);
    // ws: k bf16 3.15M | v bf16 3.15M | ao bf16 6.29M; WoT reuses k after attn.
    bf16*  kws = (bf16*)d_ws;
    bf16*  vws = kws + (size_t)M * KVN;
    bf16*  aob = vws + (size_t)M * KVN;
    bf16*  WoT = (bf16*)d_ws;                       // after attn

    cvt_x <<<4096, 256, 0, stream>>>(x, xb);
    tr_w  <<<dim3(QN / 32, Dq / 32), 256, 0, stream>>>(Wq, WqT, Dq, QN);
    tr_w  <<<dim3(LATq / 32, Dq / 32), 256, 0, stream>>>(Wkv, WkvT, Dq, LATq);
    gemm_bt128<bf16> <<<dim3(M / 128, QN / 64), 256, 0, stream>>>(xb, WqT, qws, Dq, QN);
    gemm_bt64<float> <<<dim3(M / 64, LATq / 64), 256, 0, stream>>>(xb, WkvT, xkv, Dq, LATq);
    tr_w  <<<dim3(KVN / 32, LATq / 32), 256, 0, stream>>>(Wk, WkT, LATq, KVN);
    tr_w  <<<dim3(KVN / 32, LATq / 32), 256, 0, stream>>>(Wv, WvT, LATq, KVN);
    mla_kvrms <<<M / 4, 256, 0, stream>>>(xkv, wn, latb);
    gemm_bt64<bf16> <<<dim3(M / 64, KVN / 64), 256, 0, stream>>>(latb, WkT, kws, LATq, KVN);
    gemm_bt64<bf16> <<<dim3(M / 64, KVN / 64), 256, 0, stream>>>(latb, WvT, vws, LATq, KVN);
    mla_attn <<<dim3(NLHq, 32, Bq), 256, 0, stream>>>(qws, kws, vws, aob);
    tr_w  <<<dim3(Dq / 32, QN / 32), 256, 0, stream>>>(Wo, WoT, QN, Dq);
    gemm_bt128<float> <<<dim3(M / 128, Dq / 64), 256, 0, stream>>>(aob, WoT, out, QN, Dq);
}